// Round 3
// baseline (683.889 us; speedup 1.0000x reference)
//
#include <hip/hip_runtime.h>
#include <math.h>
#include <stdint.h>

typedef unsigned int u32;
typedef unsigned short u16;
typedef __bf16 bf16x8 __attribute__((ext_vector_type(8)));
typedef float f32x4 __attribute__((ext_vector_type(4)));
typedef unsigned short u16x8 __attribute__((ext_vector_type(8)));
typedef unsigned short u16x4 __attribute__((ext_vector_type(4)));

constexpr int   Bb  = 2;
constexpr int   Ss  = 1024;
constexpr int   HID = 4096;
constexpr int   NH  = 32;
constexpr int   NKV = 8;
constexpr int   HD  = 128;
constexpr float SCALING = 0.0883883476483184405501f; // 128^-0.5

enum { M_QKV = 0, M_OUT = 3 };

// fp32 -> bf16 RTNE (bit trick; finite values only here)
__device__ __forceinline__ u16 f2bf(float f) {
  u32 u = __builtin_bit_cast(u32, f);
  u = u + 0x7fffu + ((u >> 16) & 1u);
  return (u16)(u >> 16);
}

// async global->LDS, 16B per lane, LDS dest = wave-uniform base + lane*16
__device__ __forceinline__ void gld_lds16(const void* g, void* l) {
  __builtin_amdgcn_global_load_lds(
      (const __attribute__((address_space(1))) u32*)(uintptr_t)g,
      (__attribute__((address_space(3))) u32*)(uintptr_t)l, 16, 0, 0);
}

// ---------------------------------------------------------------------------
// bf16 MFMA GEMM, m97 structure: 128x128 tile, BK=32, 256 threads (4 waves,
// 2x2), 16x16x32 MFMA, 4x4 fragments per wave. C = A * B^T with A[m][k],
// B^T[n][k] both K-contiguous. LDS XOR-swizzle on 16B slots.
// ---------------------------------------------------------------------------
template <int MODE>
__global__ __launch_bounds__(256) void mfma_gemm(
    const u16* __restrict__ Abf_g,
    const u16* __restrict__ B0, const u16* __restrict__ B1,
    const u16* __restrict__ B2,
    float* __restrict__ Cf, float* __restrict__ Ck, float* __restrict__ Cv,
    int K) {
  __shared__ u16 As[128 * 32];
  __shared__ u16 Bs[128 * 32];

  const int tid = threadIdx.x;
  const int lane = tid & 63;
  const int wid = tid >> 6;
  const int wr = wid >> 1, wc = wid & 1;

  const int m0 = blockIdx.y * 128;
  int nloc = blockIdx.x * 128;

  const u16* Abf = Abf_g + (size_t)m0 * K;
  const u16* Bp = nullptr;
  int which = 0;

  if (MODE == M_QKV) {
    const int j = blockIdx.x;  // 0..47: 32 Q col-blocks, 8 K, 8 V
    if (j < 32)      { which = 0; Bp = B0 + (size_t)j * 128 * K;        nloc = j * 128; }
    else if (j < 40) { which = 1; Bp = B1 + (size_t)(j - 32) * 128 * K; nloc = (j - 32) * 128; }
    else             { which = 2; Bp = B2 + (size_t)(j - 40) * 128 * K; nloc = (j - 40) * 128; }
  } else {  // M_OUT
    Bp = B0 + (size_t)nloc * K;
  }

  f32x4 acc[4][4];
#pragma unroll
  for (int i = 0; i < 4; i++)
#pragma unroll
    for (int j = 0; j < 4; j++) acc[i][j] = (f32x4){0.f, 0.f, 0.f, 0.f};

  const int sr = lane >> 2;  // row within 16-row chunk
  const int sp = lane & 3;   // 16B slot within 64B row
  const int fr = lane & 15;
  const int fq = lane >> 4;

  for (int kt = 0; kt < K; kt += 32) {
    __syncthreads();
#pragma unroll
    for (int cc = 0; cc < 2; ++cc) {
      const int c = wid + cc * 4;
      const int r = c * 16 + sr;
      const int sw = (r >> 1) & 3;
      const u16* ga = Abf + (size_t)r * K + kt + ((sp ^ sw) * 8);
      gld_lds16(ga, &As[c * 512]);
      const u16* gb = Bp + (size_t)r * K + kt + ((sp ^ sw) * 8);
      gld_lds16(gb, &Bs[c * 512]);
    }
    __syncthreads();

    bf16x8 av[4], bv[4];
#pragma unroll
    for (int f = 0; f < 4; ++f) {
      const int ra = wr * 64 + f * 16 + fr;
      av[f] = *(const bf16x8*)&As[ra * 32 + ((fq ^ ((ra >> 1) & 3)) * 8)];
      const int rb = wc * 64 + f * 16 + fr;
      bv[f] = *(const bf16x8*)&Bs[rb * 32 + ((fq ^ ((rb >> 1) & 3)) * 8)];
    }
#pragma unroll
    for (int i = 0; i < 4; i++)
#pragma unroll
      for (int j = 0; j < 4; j++)
        acc[i][j] = __builtin_amdgcn_mfma_f32_16x16x32_bf16(av[i], bv[j], acc[i][j], 0, 0, 0);
  }

#pragma unroll
  for (int i = 0; i < 4; i++) {
#pragma unroll
    for (int j = 0; j < 4; j++) {
      const int n = nloc + wc * 64 + j * 16 + fr;
#pragma unroll
      for (int e = 0; e < 4; e++) {
        const int m = m0 + wr * 64 + i * 16 + fq * 4 + e;
        float val = acc[i][j][e];
        if (MODE == M_QKV) {
          const int b = m >> 10, s = m & 1023, h = n >> 7, d = n & 127;
          if (which == 0)      Cf[((size_t)(b * NH + h) * Ss + s) * HD + d] = val;
          else if (which == 1) Ck[((size_t)(b * NKV + h) * Ss + s) * HD + d] = val;
          else                 Cv[((size_t)(b * NKV + h) * HD + d) * Ss + s] = val;
        } else {  // M_OUT
          Cf[(size_t)m * HID + n] = val;
        }
      }
    }
  }
}

// ---------------------------------------------------------------------------
// Fused causal attention: scores -> online m,l -> (sweep 2) quantized w write
// + PV, per (q-tile 128, bh). 4 waves, each owns 32 q-rows. K/V/Q read from
// global (L2-resident per head). P round-trips through wave-private LDS.
// ---------------------------------------------------------------------------
__device__ __forceinline__ void compute_s(const bf16x8 qf[2][4],
                                          const u16* __restrict__ Kb, int t,
                                          int fr, int fq, f32x4 sa[2][4]) {
#pragma unroll
  for (int mi = 0; mi < 2; mi++)
#pragma unroll
    for (int jn = 0; jn < 4; jn++) sa[mi][jn] = (f32x4){0.f, 0.f, 0.f, 0.f};
#pragma unroll
  for (int kk = 0; kk < 4; ++kk) {
    bf16x8 kf[4];
#pragma unroll
    for (int jn = 0; jn < 4; ++jn)
      kf[jn] = *(const bf16x8*)&Kb[((size_t)(t * 64 + jn * 16 + fr)) * HD + kk * 32 + fq * 8];
#pragma unroll
    for (int mi = 0; mi < 2; ++mi)
#pragma unroll
      for (int jn = 0; jn < 4; ++jn)
        sa[mi][jn] = __builtin_amdgcn_mfma_f32_16x16x32_bf16(qf[mi][kk], kf[jn], sa[mi][jn], 0, 0, 0);
  }
}

__global__ __launch_bounds__(256) void fused_attn(
    const u16* __restrict__ qb,   // [B*NH*S][128]
    const u16* __restrict__ kb,   // [B*NKV*S][128]
    const u16* __restrict__ vTb,  // [B*NKV][128][1024]
    float* __restrict__ wout,     // [B*NH][1024][1024]
    u16* __restrict__ attnb) {    // [B*S][4096]
  __shared__ u16 plds[4][32 * 64];  // 4 KB per wave

  const int qt = blockIdx.x;  // 0..7
  const int bh = blockIdx.y;  // 0..63
  const int b = bh >> 5, h = bh & 31;
  const int kv = h >> 2;
  const int tid = threadIdx.x;
  const int lane = tid & 63;
  const int wq = tid >> 6;
  const int fr = lane & 15, fq = lane >> 4;

  const int nt = 2 * qt + 2;          // k-tiles of 64 needed (causal)
  const int q0 = qt * 128 + wq * 32;  // wave's first q row (s index)

  const u16* Kb = kb + (size_t)(b * NKV + kv) * Ss * HD;
  const u16* Vb = vTb + (size_t)(b * NKV + kv) * HD * Ss;
  float* wrow = wout + (size_t)bh * Ss * Ss;

  // ---- zero-fill the fully-masked column range [nt*64, 1024) ----
  {
    const int z0 = nt * 64;
    const int n4 = (Ss - z0) >> 2;
    float* wr0 = wrow + (size_t)(qt * 128) * Ss + z0;
    for (int r = tid >> 3; r < 128; r += 32) {
      float4* wp = (float4*)(wr0 + (size_t)r * Ss);
      for (int c = tid & 7; c < n4; c += 8) wp[c] = float4{0.f, 0.f, 0.f, 0.f};
    }
  }

  // ---- Q fragments in registers (reused by both sweeps) ----
  bf16x8 qf[2][4];
#pragma unroll
  for (int mi = 0; mi < 2; mi++)
#pragma unroll
    for (int kk = 0; kk < 4; kk++)
      qf[mi][kk] = *(const bf16x8*)&qb[((size_t)bh * Ss + q0 + mi * 16 + fr) * HD + kk * 32 + fq * 8];

  // ---- sweep 1: online row max m and sum l (8 rows per lane) ----
  float m[8], l[8];
#pragma unroll
  for (int i = 0; i < 8; i++) { m[i] = -1e30f; l[i] = 0.f; }

  for (int t = 0; t < nt; ++t) {
    f32x4 sa[2][4];
    compute_s(qf, Kb, t, fr, fq, sa);
#pragma unroll
    for (int mi = 0; mi < 2; ++mi)
#pragma unroll
      for (int e = 0; e < 4; ++e) {
        const int ri = mi * 4 + e;
        const int qrow = q0 + mi * 16 + fq * 4 + e;
        float sv[4];
        float rmax = -1e30f;
#pragma unroll
        for (int jn = 0; jn < 4; ++jn) {
          float s = sa[mi][jn][e] * SCALING;
          const int kc = t * 64 + jn * 16 + fr;
          if (kc > qrow) s = -1e30f;
          sv[jn] = s;
          rmax = fmaxf(rmax, s);
        }
#pragma unroll
        for (int o = 1; o < 16; o <<= 1) rmax = fmaxf(rmax, __shfl_xor(rmax, o));
        const float mn = fmaxf(m[ri], rmax);
        const float c = __expf(m[ri] - mn);
        float rs = 0.f;
#pragma unroll
        for (int jn = 0; jn < 4; ++jn) rs += __expf(sv[jn] - mn);
#pragma unroll
        for (int o = 1; o < 16; o <<= 1) rs += __shfl_xor(rs, o);
        l[ri] = l[ri] * c + rs;
        m[ri] = mn;
      }
  }

  float scl[8];
#pragma unroll
  for (int i = 0; i < 8; i++) scl[i] = 1.f / (255.f * l[i]);  // = pmax/255

  // ---- sweep 2: recompute S, emit quantized w, accumulate PV ----
  f32x4 acc2[2][8];
#pragma unroll
  for (int i = 0; i < 2; i++)
#pragma unroll
    for (int j = 0; j < 8; j++) acc2[i][j] = (f32x4){0.f, 0.f, 0.f, 0.f};

  u16* pl = &plds[wq][0];

  for (int t = 0; t < nt; ++t) {
    f32x4 sa[2][4];
    compute_s(qf, Kb, t, fr, fq, sa);
#pragma unroll
    for (int mi = 0; mi < 2; ++mi)
#pragma unroll
      for (int e = 0; e < 4; ++e) {
        const int ri = mi * 4 + e;
        const int qrow = q0 + mi * 16 + fq * 4 + e;
        const int r32 = mi * 16 + fq * 4 + e;
#pragma unroll
        for (int jn = 0; jn < 4; ++jn) {
          const int kc = t * 64 + jn * 16 + fr;
          float qv = 0.f;
          if (kc <= qrow) {
            const float s = sa[mi][jn][e] * SCALING;
            qv = rintf(fminf(255.f * __expf(s - m[ri]), 255.f));
          }
          wrow[(size_t)qrow * Ss + kc] = qv * scl[ri];
          const int k64 = jn * 16 + fr;
          const int byte = r32 * 128 + (((k64 >> 3) ^ (r32 & 7)) * 16) + (k64 & 7) * 2;
          *(u16*)((char*)pl + byte) = f2bf(qv);  // integers 0..255: exact
        }
      }
    // PV: A = P (LDS, wave-private), B = V^T rows from global (L2-resident)
#pragma unroll
    for (int kk2 = 0; kk2 < 2; ++kk2) {
      bf16x8 pa[2];
#pragma unroll
      for (int mi2 = 0; mi2 < 2; ++mi2) {
        const int row = mi2 * 16 + fr;
        const int slot = (kk2 * 4 + fq) ^ (row & 7);
        pa[mi2] = *(const bf16x8*)((char*)pl + row * 128 + slot * 16);
      }
#pragma unroll
      for (int jn2 = 0; jn2 < 8; ++jn2) {
        const bf16x8 vb = *(const bf16x8*)&Vb[(size_t)(jn2 * 16 + fr) * Ss + t * 64 + kk2 * 32 + fq * 8];
#pragma unroll
        for (int mi2 = 0; mi2 < 2; ++mi2)
          acc2[mi2][jn2] = __builtin_amdgcn_mfma_f32_16x16x32_bf16(pa[mi2], vb, acc2[mi2][jn2], 0, 0, 0);
      }
    }
  }

  // ---- epilogue: attn = acc2 * scale -> bf16 [B*S][NH*HD] ----
#pragma unroll
  for (int mi2 = 0; mi2 < 2; ++mi2)
#pragma unroll
    for (int e = 0; e < 4; ++e) {
      const int ri = mi2 * 4 + e;
      const int qrow = q0 + mi2 * 16 + fq * 4 + e;
#pragma unroll
      for (int jn2 = 0; jn2 < 8; ++jn2)
        attnb[((size_t)b * Ss + qrow) * HID + h * HD + jn2 * 16 + fr] =
            f2bf(acc2[mi2][jn2][e] * scl[ri]);
    }
}

// ---------------------------------------------------------------------------
// fp32 -> bf16 conversion, 8 elems/thread
__global__ __launch_bounds__(256) void f32_to_bf16_k(const float* __restrict__ in,
                                                     u16* __restrict__ out, int n8) {
  const int i = blockIdx.x * 256 + threadIdx.x;
  if (i < n8) {
    float4 a = ((const float4*)in)[2 * i];
    float4 b = ((const float4*)in)[2 * i + 1];
    u16x8 t;
    t[0] = f2bf(a.x); t[1] = f2bf(a.y); t[2] = f2bf(a.z); t[3] = f2bf(a.w);
    t[4] = f2bf(b.x); t[5] = f2bf(b.y); t[6] = f2bf(b.z); t[7] = f2bf(b.w);
    ((u16x8*)out)[i] = t;
  }
}

// RoPE + per-row asymmetric 8-bit fake-quant for q -> bf16. One wave per row.
__global__ __launch_bounds__(256) void rope_quant_q(const float* __restrict__ q,
                                                    u16* __restrict__ qb,
                                                    const float* __restrict__ cs,
                                                    const float* __restrict__ sn) {
  const int row = blockIdx.x * 4 + (threadIdx.x >> 6);
  const int lane = threadIdx.x & 63;
  const int s = row & (Ss - 1);
  const int b = row >> 15;
  const float* p = q + (size_t)row * HD;
  const float* cp = cs + ((size_t)b * Ss + s) * HD;
  const float* sp = sn + ((size_t)b * Ss + s) * HD;
  float x1 = p[lane], x2 = p[lane + 64];
  float r1 = x1 * cp[lane] - x2 * sp[lane];
  float r2 = x2 * cp[lane + 64] + x1 * sp[lane + 64];
  float mn = fminf(0.f, fminf(r1, r2));
  float mx = fmaxf(0.f, fmaxf(r1, r2));
#pragma unroll
  for (int o = 32; o; o >>= 1) {
    mn = fminf(mn, __shfl_xor(mn, o));
    mx = fmaxf(mx, __shfl_xor(mx, o));
  }
  float rng = mx - mn;
  float scale = (rng == 0.f) ? 1.f : rng / 255.f;
  float zero = rintf(-mn / scale);
  float q1 = fminf(fmaxf(rintf(r1 / scale) + zero, 0.f), 255.f);
  float q2 = fminf(fmaxf(rintf(r2 / scale) + zero, 0.f), 255.f);
  qb[(size_t)row * HD + lane] = f2bf((q1 - zero) * scale);
  qb[(size_t)row * HD + lane + 64] = f2bf((q2 - zero) * scale);
}

// RoPE only for k. One wave per row, in place.
__global__ __launch_bounds__(256) void rope_k(float* __restrict__ k,
                                              const float* __restrict__ cs,
                                              const float* __restrict__ sn) {
  const int row = blockIdx.x * 4 + (threadIdx.x >> 6);
  const int lane = threadIdx.x & 63;
  const int s = row & (Ss - 1);
  const int b = row >> 13;
  float* p = k + (size_t)row * HD;
  const float* cp = cs + ((size_t)b * Ss + s) * HD;
  const float* sp = sn + ((size_t)b * Ss + s) * HD;
  float x1 = p[lane], x2 = p[lane + 64];
  float r1 = x1 * cp[lane] - x2 * sp[lane];
  float r2 = x2 * cp[lane + 64] + x1 * sp[lane + 64];
  p[lane] = r1;
  p[lane + 64] = r2;
}

// Mean of k over S per (b,h,d). One 1024-thread block per (b,h).
__global__ __launch_bounds__(1024) void kmean_kernel(const float* __restrict__ k,
                                                     float* __restrict__ kmean) {
  const int bh = blockIdx.x;
  const int d = threadIdx.x & 127;
  const int sl = threadIdx.x >> 7;
  const float* p = k + (size_t)bh * Ss * HD;
  float sum = 0.f;
  for (int s = sl; s < Ss; s += 8) sum += p[(size_t)s * HD + d];
  __shared__ float lds[8][128];
  lds[sl][d] = sum;
  __syncthreads();
  if (threadIdx.x < 128) {
    float t = 0.f;
#pragma unroll
    for (int i = 0; i < 8; i++) t += lds[i][threadIdx.x];
    kmean[bh * HD + threadIdx.x] = t * (1.f / 1024.f);
  }
}

// Subtract mean + per-row quant for k -> bf16. One wave per row.
__global__ __launch_bounds__(256) void k_subquant(const float* __restrict__ k,
                                                  u16* __restrict__ kb,
                                                  const float* __restrict__ kmean) {
  const int row = blockIdx.x * 4 + (threadIdx.x >> 6);
  const int lane = threadIdx.x & 63;
  const int bh = row >> 10;
  const float* p = k + (size_t)row * HD;
  float x1 = p[lane] - kmean[bh * HD + lane];
  float x2 = p[lane + 64] - kmean[bh * HD + lane + 64];
  float mn = fminf(0.f, fminf(x1, x2));
  float mx = fmaxf(0.f, fmaxf(x1, x2));
#pragma unroll
  for (int o = 32; o; o >>= 1) {
    mn = fminf(mn, __shfl_xor(mn, o));
    mx = fmaxf(mx, __shfl_xor(mx, o));
  }
  float rng = mx - mn;
  float scale = (rng == 0.f) ? 1.f : rng / 255.f;
  float zero = rintf(-mn / scale);
  float q1 = fminf(fmaxf(rintf(x1 / scale) + zero, 0.f), 255.f);
  float q2 = fminf(fmaxf(rintf(x2 / scale) + zero, 0.f), 255.f);
  kb[(size_t)row * HD + lane] = f2bf((q1 - zero) * scale);
  kb[(size_t)row * HD + lane + 64] = f2bf((q2 - zero) * scale);
}

// Per-(b,h,d) quant of v over S (vT rows) -> bf16. One block per row.
__global__ __launch_bounds__(256) void vquant(const float* __restrict__ vT,
                                              u16* __restrict__ vTb) {
  const float* p = vT + (size_t)blockIdx.x * Ss;
  const int t = threadIdx.x;
  float4 x = ((const float4*)p)[t];
  float mn = fminf(0.f, fminf(fminf(x.x, x.y), fminf(x.z, x.w)));
  float mx = fmaxf(0.f, fmaxf(fmaxf(x.x, x.y), fmaxf(x.z, x.w)));
#pragma unroll
  for (int o = 32; o; o >>= 1) {
    mn = fminf(mn, __shfl_xor(mn, o));
    mx = fmaxf(mx, __shfl_xor(mx, o));
  }
  __shared__ float smn[4], smx[4];
  const int wid = t >> 6, lane = t & 63;
  if (lane == 0) { smn[wid] = mn; smx[wid] = mx; }
  __syncthreads();
  mn = fminf(fminf(smn[0], smn[1]), fminf(smn[2], smn[3]));
  mx = fmaxf(fmaxf(smx[0], smx[1]), fmaxf(smx[2], smx[3]));
  float rng = mx - mn;
  float scale = (rng == 0.f) ? 1.f : rng / 255.f;
  float zero = rintf(-mn / scale);
  u16x4 o4;
  o4[0] = f2bf((fminf(fmaxf(rintf(x.x / scale) + zero, 0.f), 255.f) - zero) * scale);
  o4[1] = f2bf((fminf(fmaxf(rintf(x.y / scale) + zero, 0.f), 255.f) - zero) * scale);
  o4[2] = f2bf((fminf(fmaxf(rintf(x.z / scale) + zero, 0.f), 255.f) - zero) * scale);
  o4[3] = f2bf((fminf(fmaxf(rintf(x.w / scale) + zero, 0.f), 255.f) - zero) * scale);
  ((u16x4*)vTb)[(size_t)blockIdx.x * 256 + t] = o4;
}

// ---------------------------------------------------------------------------
extern "C" void kernel_launch(void* const* d_in, const int* in_sizes, int n_in,
                              void* d_out, int out_size, void* d_ws, size_t ws_size,
                              hipStream_t stream) {
  const float* hs = (const float*)d_in[0];
  const float* cosp = (const float*)d_in[1];
  const float* sinp = (const float*)d_in[2];
  const float* Wq = (const float*)d_in[4];
  const float* Wk = (const float*)d_in[5];
  const float* Wv = (const float*)d_in[6];
  const float* Wo = (const float*)d_in[7];

  float* out = (float*)d_out;
  float* wout = out + (size_t)Bb * Ss * HID;  // w output region (fp32)

  char* wsp = (char*)d_ws;
  auto alloc = [&](size_t bytes) {
    char* p = wsp;
    wsp += (bytes + 255) & ~(size_t)255;
    return p;
  };
  float* q     = (float*)alloc((size_t)Bb * NH * Ss * HD * 4);   // 33.6 MB
  float* k     = (float*)alloc((size_t)Bb * NKV * Ss * HD * 4);  // 8.4 MB
  float* vT    = (float*)alloc((size_t)Bb * NKV * Ss * HD * 4);  // 8.4 MB
  float* kmean = (float*)alloc((size_t)Bb * NKV * HD * 4);
  u16* hsb = (u16*)alloc((size_t)Bb * Ss * HID * 2);
  u16* qb  = (u16*)alloc((size_t)Bb * NH * Ss * HD * 2);
  u16* kb  = (u16*)alloc((size_t)Bb * NKV * Ss * HD * 2);
  u16* vTb = (u16*)alloc((size_t)Bb * NKV * Ss * HD * 2);
  u16* Wqb = (u16*)alloc((size_t)NH * HD * HID * 2);
  u16* Wkb = (u16*)alloc((size_t)NKV * HD * HID * 2);
  u16* Wvb = (u16*)alloc((size_t)NKV * HD * HID * 2);
  u16* Wob = (u16*)alloc((size_t)HID * NH * HD * 2);
  u16* attnb = (u16*)q;  // q fp32 dead after rope_quant_q; reuse

  // fp32 -> bf16 conversions
  f32_to_bf16_k<<<(Bb * Ss * HID / 8 + 255) / 256, 256, 0, stream>>>(hs, hsb, Bb * Ss * HID / 8);
  f32_to_bf16_k<<<(NH * HD * HID / 8 + 255) / 256, 256, 0, stream>>>(Wq, Wqb, NH * HD * HID / 8);
  f32_to_bf16_k<<<(NKV * HD * HID / 8 + 255) / 256, 256, 0, stream>>>(Wk, Wkb, NKV * HD * HID / 8);
  f32_to_bf16_k<<<(NKV * HD * HID / 8 + 255) / 256, 256, 0, stream>>>(Wv, Wvb, NKV * HD * HID / 8);
  f32_to_bf16_k<<<(HID * NH * HD / 8 + 255) / 256, 256, 0, stream>>>(Wo, Wob, HID * NH * HD / 8);

  // fused Q/K/V projection
  mfma_gemm<M_QKV><<<dim3(48, 16, 1), 256, 0, stream>>>(
      hsb, Wqb, Wkb, Wvb, q, k, vT, HID);

  // RoPE / mean-center / quantize
  rope_quant_q<<<(Bb * NH * Ss) / 4, 256, 0, stream>>>(q, qb, cosp, sinp);
  rope_k<<<(Bb * NKV * Ss) / 4, 256, 0, stream>>>(k, cosp, sinp);
  kmean_kernel<<<Bb * NKV, 1024, 0, stream>>>(k, kmean);
  k_subquant<<<(Bb * NKV * Ss) / 4, 256, 0, stream>>>(k, kb, kmean);
  vquant<<<Bb * NKV * HD, 256, 0, stream>>>(vT, vTb);

  // fused scores+softmax+quant(w)+PV
  fused_attn<<<dim3(8, Bb * NH), 256, 0, stream>>>(qb, kb, vTb, wout, attnb);

  // out = attn @ Wo^T (fp32 out)
  mfma_gemm<M_OUT><<<dim3(32, 16, 1), 256, 0, stream>>>(
      attnb, Wob, nullptr, nullptr, out, nullptr, nullptr, HID);
}

// Round 4
// 509.743 us; speedup vs baseline: 1.3416x; 1.3416x over previous
//
#include <hip/hip_runtime.h>
#include <math.h>
#include <stdint.h>

typedef unsigned int u32;
typedef unsigned short u16;
typedef __bf16 bf16x8 __attribute__((ext_vector_type(8)));
typedef float f32x4 __attribute__((ext_vector_type(4)));
typedef unsigned short u16x8 __attribute__((ext_vector_type(8)));
typedef unsigned short u16x4 __attribute__((ext_vector_type(4)));

constexpr int   Bb  = 2;
constexpr int   Ss  = 1024;
constexpr int   HID = 4096;
constexpr int   NH  = 32;
constexpr int   NKV = 8;
constexpr int   HD  = 128;
constexpr float SCALING = 0.0883883476483184405501f; // 128^-0.5

enum { M_QKV = 0, M_OUT = 3 };

// fp32 -> bf16 RTNE (bit trick; finite values only here)
__device__ __forceinline__ u16 f2bf(float f) {
  u32 u = __builtin_bit_cast(u32, f);
  u = u + 0x7fffu + ((u >> 16) & 1u);
  return (u16)(u >> 16);
}

// async global->LDS, 16B per lane; LDS dest = wave-uniform base (+ lane*16 by HW)
__device__ __forceinline__ void gld_lds16(const void* g, void* l) {
  __builtin_amdgcn_global_load_lds(
      (const __attribute__((address_space(1))) u32*)(uintptr_t)g,
      (__attribute__((address_space(3))) u32*)(uintptr_t)l, 16, 0, 0);
}

// ---------------------------------------------------------------------------
// bf16 MFMA GEMM, m97 structure (unchanged from R3; QKV + OUT projections).
// ---------------------------------------------------------------------------
template <int MODE>
__global__ __launch_bounds__(256) void mfma_gemm(
    const u16* __restrict__ Abf_g,
    const u16* __restrict__ B0, const u16* __restrict__ B1,
    const u16* __restrict__ B2,
    float* __restrict__ Cf, float* __restrict__ Ck, float* __restrict__ Cv,
    int K) {
  __shared__ u16 As[128 * 32];
  __shared__ u16 Bs[128 * 32];

  const int tid = threadIdx.x;
  const int lane = tid & 63;
  const int wid = tid >> 6;
  const int wr = wid >> 1, wc = wid & 1;

  const int m0 = blockIdx.y * 128;
  int nloc = blockIdx.x * 128;

  const u16* Abf = Abf_g + (size_t)m0 * K;
  const u16* Bp = nullptr;
  int which = 0;

  if (MODE == M_QKV) {
    const int j = blockIdx.x;  // 0..47: 32 Q col-blocks, 8 K, 8 V
    if (j < 32)      { which = 0; Bp = B0 + (size_t)j * 128 * K;        nloc = j * 128; }
    else if (j < 40) { which = 1; Bp = B1 + (size_t)(j - 32) * 128 * K; nloc = (j - 32) * 128; }
    else             { which = 2; Bp = B2 + (size_t)(j - 40) * 128 * K; nloc = (j - 40) * 128; }
  } else {  // M_OUT
    Bp = B0 + (size_t)nloc * K;
  }

  f32x4 acc[4][4];
#pragma unroll
  for (int i = 0; i < 4; i++)
#pragma unroll
    for (int j = 0; j < 4; j++) acc[i][j] = (f32x4){0.f, 0.f, 0.f, 0.f};

  const int sr = lane >> 2;
  const int sp = lane & 3;
  const int fr = lane & 15;
  const int fq = lane >> 4;

  for (int kt = 0; kt < K; kt += 32) {
    __syncthreads();
#pragma unroll
    for (int cc = 0; cc < 2; ++cc) {
      const int c = wid + cc * 4;
      const int r = c * 16 + sr;
      const int sw = (r >> 1) & 3;
      const u16* ga = Abf + (size_t)r * K + kt + ((sp ^ sw) * 8);
      gld_lds16(ga, &As[c * 512]);
      const u16* gb = Bp + (size_t)r * K + kt + ((sp ^ sw) * 8);
      gld_lds16(gb, &Bs[c * 512]);
    }
    __syncthreads();

    bf16x8 av[4], bv[4];
#pragma unroll
    for (int f = 0; f < 4; ++f) {
      const int ra = wr * 64 + f * 16 + fr;
      av[f] = *(const bf16x8*)&As[ra * 32 + ((fq ^ ((ra >> 1) & 3)) * 8)];
      const int rb = wc * 64 + f * 16 + fr;
      bv[f] = *(const bf16x8*)&Bs[rb * 32 + ((fq ^ ((rb >> 1) & 3)) * 8)];
    }
#pragma unroll
    for (int i = 0; i < 4; i++)
#pragma unroll
      for (int j = 0; j < 4; j++)
        acc[i][j] = __builtin_amdgcn_mfma_f32_16x16x32_bf16(av[i], bv[j], acc[i][j], 0, 0, 0);
  }

#pragma unroll
  for (int i = 0; i < 4; i++) {
#pragma unroll
    for (int j = 0; j < 4; j++) {
      const int n = nloc + wc * 64 + j * 16 + fr;
#pragma unroll
      for (int e = 0; e < 4; e++) {
        const int m = m0 + wr * 64 + i * 16 + fq * 4 + e;
        float val = acc[i][j][e];
        if (MODE == M_QKV) {
          const int b = m >> 10, s = m & 1023, h = n >> 7, d = n & 127;
          if (which == 0)      Cf[((size_t)(b * NH + h) * Ss + s) * HD + d] = val;
          else if (which == 1) Ck[((size_t)(b * NKV + h) * Ss + s) * HD + d] = val;
          else                 Cv[((size_t)(b * NKV + h) * HD + d) * Ss + s] = val;
        } else {  // M_OUT
          Cf[(size_t)m * HID + n] = val;
        }
      }
    }
  }
}

// ---------------------------------------------------------------------------
// Fused causal attention, block-cooperative:
//   block = (a, bh): 64 q-rows (Q0 = a*64), 4 waves x 16 rows, nt = a+1 k-tiles.
//   Sweep 1: K staged in LDS -> online (m,l).  Sweep 2: K+V staged -> recompute
//   S (bit-identical), emit quantized w (vectorized via LDS round-trip), PV.
// LDS tiles XOR-swizzled; K/V staged with pre-swizzled global sources.
// ---------------------------------------------------------------------------
__global__ __launch_bounds__(256) void fused_attn(
    const u16* __restrict__ qb,   // [B*NH*S][128]
    const u16* __restrict__ kb,   // [B*NKV*S][128]
    const u16* __restrict__ vTb,  // [B*NKV][128][1024]
    float* __restrict__ wout,     // [B*NH][1024][1024]
    u16* __restrict__ attnb) {    // [B*S][4096]
  __shared__ u16 Ks[64 * 128];    // 16 KB: [row 64][d 128], 16B-slot swizzle ^(row&15)
  __shared__ u16 Vs[128 * 64];    // 16 KB: [d 128][k 64],  16B-slot swizzle ^(d&7)
  __shared__ u16 plds[4][16 * 64];  // 2 KB/wave: [row 16][k 64], slot swizzle ^(row&7)
  __shared__ float scl_l[4][16];

  const int a = 15 - (int)(blockIdx.x >> 6);  // heavy blocks first
  const int bh = blockIdx.x & 63;
  const int b = bh >> 5, h = bh & 31;
  const int kv = h >> 2;
  const int tid = threadIdx.x;
  const int lane = tid & 63;
  const int wq = tid >> 6;
  const int fr = lane & 15, fq = lane >> 4;

  const int nt = a + 1;
  const int Q0 = a * 64;
  const int qw0 = Q0 + wq * 16;  // wave's first q row

  const u16* Kb = kb + (size_t)(b * NKV + kv) * Ss * HD;
  const u16* Vb = vTb + (size_t)(b * NKV + kv) * HD * Ss;
  float* wrow = wout + (size_t)bh * Ss * Ss;

  // ---- zero-fill fully-masked columns [nt*64, 1024) for this row block ----
  if (a < 15) {
    const int base = 64 * nt;
    const int n4 = 16 * (15 - a);
#pragma unroll
    for (int r0 = 0; r0 < 4; ++r0) {
      const int row = Q0 + r0 * 16 + (tid >> 4);
      float4* wp = (float4*)&wrow[(size_t)row * Ss + base];
      for (int c = tid & 15; c < n4; c += 16) wp[c] = float4{0.f, 0.f, 0.f, 0.f};
    }
  }

  // ---- Q fragments (rows qw0+fr), reused by both sweeps ----
  bf16x8 qf[4];
#pragma unroll
  for (int kk = 0; kk < 4; kk++)
    qf[kk] = *(const bf16x8*)&qb[((size_t)bh * Ss + qw0 + fr) * HD + kk * 32 + fq * 8];

  // ================= sweep 1: online m, l =================
  float m[4], l[4];
#pragma unroll
  for (int i = 0; i < 4; i++) { m[i] = -1e30f; l[i] = 0.f; }

  for (int t = 0; t < nt; ++t) {
    __syncthreads();
    // stage K tile t (block-cooperative, pre-swizzled source)
#pragma unroll
    for (int c = 0; c < 4; ++c) {
      const int idx0 = (c * 4 + wq) * 64;
      const int idx = idx0 + lane;
      const int row = idx >> 4, sl = idx & 15;
      const int slot = sl ^ (row & 15);
      gld_lds16(Kb + (size_t)(t * 64 + row) * HD + slot * 8, &Ks[idx0 * 8]);
    }
    __syncthreads();

    f32x4 sa[4];
#pragma unroll
    for (int jn = 0; jn < 4; jn++) sa[jn] = (f32x4){0.f, 0.f, 0.f, 0.f};
#pragma unroll
    for (int kk = 0; kk < 4; ++kk) {
      bf16x8 kfv[4];
#pragma unroll
      for (int jn = 0; jn < 4; ++jn) {
        const int row = jn * 16 + fr;
        kfv[jn] = *(const bf16x8*)&Ks[row * 128 + (((kk * 4 + fq) ^ fr) * 8)];
      }
#pragma unroll
      for (int jn = 0; jn < 4; ++jn)
        sa[jn] = __builtin_amdgcn_mfma_f32_16x16x32_bf16(qf[kk], kfv[jn], sa[jn], 0, 0, 0);
    }

    const bool diag = (t == a);
#pragma unroll
    for (int e = 0; e < 4; ++e) {
      const int qrow = qw0 + fq * 4 + e;
      float sv[4];
      float rmax = -1e30f;
#pragma unroll
      for (int jn = 0; jn < 4; ++jn) {
        float s = sa[jn][e] * SCALING;
        if (diag && (t * 64 + jn * 16 + fr > qrow)) s = -1e30f;
        sv[jn] = s;
        rmax = fmaxf(rmax, s);
      }
#pragma unroll
      for (int o = 1; o < 16; o <<= 1) rmax = fmaxf(rmax, __shfl_xor(rmax, o));
      const float mn = fmaxf(m[e], rmax);
      const float cc = __expf(m[e] - mn);
      float rs = __expf(sv[0] - mn) + __expf(sv[1] - mn) +
                 __expf(sv[2] - mn) + __expf(sv[3] - mn);
#pragma unroll
      for (int o = 1; o < 16; o <<= 1) rs += __shfl_xor(rs, o);
      l[e] = l[e] * cc + rs;
      m[e] = mn;
    }
  }

  float scl[4];
#pragma unroll
  for (int e = 0; e < 4; e++) scl[e] = 1.f / (255.f * l[e]);
  if (fr == 0) {
#pragma unroll
    for (int e = 0; e < 4; e++) scl_l[wq][fq * 4 + e] = scl[e];
  }

  // ================= sweep 2: emit w + PV =================
  f32x4 acc2[8];
#pragma unroll
  for (int j = 0; j < 8; j++) acc2[j] = (f32x4){0.f, 0.f, 0.f, 0.f};

  u16* pl = &plds[wq][0];
  const int wrrow = lane >> 2, wrq = lane & 3;  // w readback mapping
  const float sclr = scl_l[wq][wrrow];

  for (int t = 0; t < nt; ++t) {
    __syncthreads();
    // stage K + V tiles (8 insts per wave total)
#pragma unroll
    for (int c = 0; c < 4; ++c) {
      const int idx0 = (c * 4 + wq) * 64;
      const int idx = idx0 + lane;
      {
        const int row = idx >> 4, sl = idx & 15;
        const int slot = sl ^ (row & 15);
        gld_lds16(Kb + (size_t)(t * 64 + row) * HD + slot * 8, &Ks[idx0 * 8]);
      }
      {
        const int d = idx >> 3, sl = idx & 7;
        const int slot = sl ^ (d & 7);
        gld_lds16(Vb + (size_t)d * Ss + t * 64 + slot * 8, &Vs[idx0 * 8]);
      }
    }
    __syncthreads();

    // S recompute — bit-identical order to sweep 1
    f32x4 sa[4];
#pragma unroll
    for (int jn = 0; jn < 4; jn++) sa[jn] = (f32x4){0.f, 0.f, 0.f, 0.f};
#pragma unroll
    for (int kk = 0; kk < 4; ++kk) {
      bf16x8 kfv[4];
#pragma unroll
      for (int jn = 0; jn < 4; ++jn) {
        const int row = jn * 16 + fr;
        kfv[jn] = *(const bf16x8*)&Ks[row * 128 + (((kk * 4 + fq) ^ fr) * 8)];
      }
#pragma unroll
      for (int jn = 0; jn < 4; ++jn)
        sa[jn] = __builtin_amdgcn_mfma_f32_16x16x32_bf16(qf[kk], kfv[jn], sa[jn], 0, 0, 0);
    }

    // quantize -> integer P into wave-private LDS (bf16 ints are exact)
    const bool diag = (t == a);
#pragma unroll
    for (int e = 0; e < 4; ++e) {
      const int qrow = qw0 + fq * 4 + e;
      const int r16 = fq * 4 + e;
#pragma unroll
      for (int jn = 0; jn < 4; ++jn) {
        const int kc = t * 64 + jn * 16 + fr;
        float qv = 0.f;
        if (!diag || kc <= qrow)
          qv = rintf(fminf(255.f * __expf(sa[jn][e] * SCALING - m[e]), 255.f));
        const int col = jn * 16 + fr;
        const int byte = r16 * 128 + (((col >> 3) ^ (r16 & 7)) * 16) + (col & 7) * 2;
        *(u16*)((char*)pl + byte) = f2bf(qv);
      }
    }

    // vectorized w write: LDS -> float4 stores (lane: row=lane>>2, 16-col quarter)
    {
      const int s0 = (2 * wrq) ^ (wrrow & 7);
      const int s1 = (2 * wrq + 1) ^ (wrrow & 7);
      bf16x8 p0 = *(const bf16x8*)((char*)pl + wrrow * 128 + s0 * 16);
      bf16x8 p1 = *(const bf16x8*)((char*)pl + wrrow * 128 + s1 * 16);
      float* wp = &wrow[(size_t)(qw0 + wrrow) * Ss + t * 64 + wrq * 16];
      float4 o0, o1, o2, o3;
      o0.x = (float)p0[0] * sclr; o0.y = (float)p0[1] * sclr;
      o0.z = (float)p0[2] * sclr; o0.w = (float)p0[3] * sclr;
      o1.x = (float)p0[4] * sclr; o1.y = (float)p0[5] * sclr;
      o1.z = (float)p0[6] * sclr; o1.w = (float)p0[7] * sclr;
      o2.x = (float)p1[0] * sclr; o2.y = (float)p1[1] * sclr;
      o2.z = (float)p1[2] * sclr; o2.w = (float)p1[3] * sclr;
      o3.x = (float)p1[4] * sclr; o3.y = (float)p1[5] * sclr;
      o3.z = (float)p1[6] * sclr; o3.w = (float)p1[7] * sclr;
      ((float4*)wp)[0] = o0; ((float4*)wp)[1] = o1;
      ((float4*)wp)[2] = o2; ((float4*)wp)[3] = o3;
    }

    // PV: A = P ints (LDS), B = V^T (LDS)
#pragma unroll
    for (int kk2 = 0; kk2 < 2; ++kk2) {
      const bf16x8 pa = *(const bf16x8*)((char*)pl + fr * 128 + (((kk2 * 4 + fq) ^ (fr & 7)) * 16));
#pragma unroll
      for (int jn2 = 0; jn2 < 8; ++jn2) {
        const int d = jn2 * 16 + fr;
        const bf16x8 vb = *(const bf16x8*)&Vs[d * 64 + (((kk2 * 4 + fq) ^ (d & 7)) * 8)];
        acc2[jn2] = __builtin_amdgcn_mfma_f32_16x16x32_bf16(pa, vb, acc2[jn2], 0, 0, 0);
      }
    }
  }

  // ---- epilogue: attn -> bf16 [B*S][NH*HD] ----
#pragma unroll
  for (int e = 0; e < 4; ++e) {
    const int qrow = qw0 + fq * 4 + e;
#pragma unroll
    for (int jn2 = 0; jn2 < 8; ++jn2)
      attnb[((size_t)b * Ss + qrow) * HID + h * HD + jn2 * 16 + fr] =
          f2bf(acc2[jn2][e] * scl[e]);
  }
}

// ---------------------------------------------------------------------------
// fp32 -> bf16 conversion, 8 elems/thread
__global__ __launch_bounds__(256) void f32_to_bf16_k(const float* __restrict__ in,
                                                     u16* __restrict__ out, int n8) {
  const int i = blockIdx.x * 256 + threadIdx.x;
  if (i < n8) {
    float4 a = ((const float4*)in)[2 * i];
    float4 b = ((const float4*)in)[2 * i + 1];
    u16x8 t;
    t[0] = f2bf(a.x); t[1] = f2bf(a.y); t[2] = f2bf(a.z); t[3] = f2bf(a.w);
    t[4] = f2bf(b.x); t[5] = f2bf(b.y); t[6] = f2bf(b.z); t[7] = f2bf(b.w);
    ((u16x8*)out)[i] = t;
  }
}

// RoPE + per-row asymmetric 8-bit fake-quant for q -> bf16. One wave per row.
__global__ __launch_bounds__(256) void rope_quant_q(const float* __restrict__ q,
                                                    u16* __restrict__ qb,
                                                    const float* __restrict__ cs,
                                                    const float* __restrict__ sn) {
  const int row = blockIdx.x * 4 + (threadIdx.x >> 6);
  const int lane = threadIdx.x & 63;
  const int s = row & (Ss - 1);
  const int b = row >> 15;
  const float* p = q + (size_t)row * HD;
  const float* cp = cs + ((size_t)b * Ss + s) * HD;
  const float* sp = sn + ((size_t)b * Ss + s) * HD;
  float x1 = p[lane], x2 = p[lane + 64];
  float r1 = x1 * cp[lane] - x2 * sp[lane];
  float r2 = x2 * cp[lane + 64] + x1 * sp[lane + 64];
  float mn = fminf(0.f, fminf(r1, r2));
  float mx = fmaxf(0.f, fmaxf(r1, r2));
#pragma unroll
  for (int o = 32; o; o >>= 1) {
    mn = fminf(mn, __shfl_xor(mn, o));
    mx = fmaxf(mx, __shfl_xor(mx, o));
  }
  float rng = mx - mn;
  float scale = (rng == 0.f) ? 1.f : rng / 255.f;
  float zero = rintf(-mn / scale);
  float q1 = fminf(fmaxf(rintf(r1 / scale) + zero, 0.f), 255.f);
  float q2 = fminf(fmaxf(rintf(r2 / scale) + zero, 0.f), 255.f);
  qb[(size_t)row * HD + lane] = f2bf((q1 - zero) * scale);
  qb[(size_t)row * HD + lane + 64] = f2bf((q2 - zero) * scale);
}

// RoPE only for k. One wave per row, in place.
__global__ __launch_bounds__(256) void rope_k(float* __restrict__ k,
                                              const float* __restrict__ cs,
                                              const float* __restrict__ sn) {
  const int row = blockIdx.x * 4 + (threadIdx.x >> 6);
  const int lane = threadIdx.x & 63;
  const int s = row & (Ss - 1);
  const int b = row >> 13;
  float* p = k + (size_t)row * HD;
  const float* cp = cs + ((size_t)b * Ss + s) * HD;
  const float* sp = sn + ((size_t)b * Ss + s) * HD;
  float x1 = p[lane], x2 = p[lane + 64];
  float r1 = x1 * cp[lane] - x2 * sp[lane];
  float r2 = x2 * cp[lane + 64] + x1 * sp[lane + 64];
  p[lane] = r1;
  p[lane + 64] = r2;
}

// Mean of k over S per (b,h,d). One 1024-thread block per (b,h).
__global__ __launch_bounds__(1024) void kmean_kernel(const float* __restrict__ k,
                                                     float* __restrict__ kmean) {
  const int bh = blockIdx.x;
  const int d = threadIdx.x & 127;
  const int sl = threadIdx.x >> 7;
  const float* p = k + (size_t)bh * Ss * HD;
  float sum = 0.f;
  for (int s = sl; s < Ss; s += 8) sum += p[(size_t)s * HD + d];
  __shared__ float lds[8][128];
  lds[sl][d] = sum;
  __syncthreads();
  if (threadIdx.x < 128) {
    float t = 0.f;
#pragma unroll
    for (int i = 0; i < 8; i++) t += lds[i][threadIdx.x];
    kmean[bh * HD + threadIdx.x] = t * (1.f / 1024.f);
  }
}

// Subtract mean + per-row quant for k -> bf16. One wave per row.
__global__ __launch_bounds__(256) void k_subquant(const float* __restrict__ k,
                                                  u16* __restrict__ kb,
                                                  const float* __restrict__ kmean) {
  const int row = blockIdx.x * 4 + (threadIdx.x >> 6);
  const int lane = threadIdx.x & 63;
  const int bh = row >> 10;
  const float* p = k + (size_t)row * HD;
  float x1 = p[lane] - kmean[bh * HD + lane];
  float x2 = p[lane + 64] - kmean[bh * HD + lane + 64];
  float mn = fminf(0.f, fminf(x1, x2));
  float mx = fmaxf(0.f, fmaxf(x1, x2));
#pragma unroll
  for (int o = 32; o; o >>= 1) {
    mn = fminf(mn, __shfl_xor(mn, o));
    mx = fmaxf(mx, __shfl_xor(mx, o));
  }
  float rng = mx - mn;
  float scale = (rng == 0.f) ? 1.f : rng / 255.f;
  float zero = rintf(-mn / scale);
  float q1 = fminf(fmaxf(rintf(x1 / scale) + zero, 0.f), 255.f);
  float q2 = fminf(fmaxf(rintf(x2 / scale) + zero, 0.f), 255.f);
  kb[(size_t)row * HD + lane] = f2bf((q1 - zero) * scale);
  kb[(size_t)row * HD + lane + 64] = f2bf((q2 - zero) * scale);
}

// Per-(b,h,d) quant of v over S (vT rows) -> bf16. One block per row.
__global__ __launch_bounds__(256) void vquant(const float* __restrict__ vT,
                                              u16* __restrict__ vTb) {
  const float* p = vT + (size_t)blockIdx.x * Ss;
  const int t = threadIdx.x;
  float4 x = ((const float4*)p)[t];
  float mn = fminf(0.f, fminf(fminf(x.x, x.y), fminf(x.z, x.w)));
  float mx = fmaxf(0.f, fmaxf(fmaxf(x.x, x.y), fmaxf(x.z, x.w)));
#pragma unroll
  for (int o = 32; o; o >>= 1) {
    mn = fminf(mn, __shfl_xor(mn, o));
    mx = fmaxf(mx, __shfl_xor(mx, o));
  }
  __shared__ float smn[4], smx[4];
  const int wid = t >> 6, lane = t & 63;
  if (lane == 0) { smn[wid] = mn; smx[wid] = mx; }
  __syncthreads();
  mn = fminf(fminf(smn[0], smn[1]), fminf(smn[2], smn[3]));
  mx = fmaxf(fmaxf(smx[0], smx[1]), fmaxf(smx[2], smx[3]));
  float rng = mx - mn;
  float scale = (rng == 0.f) ? 1.f : rng / 255.f;
  float zero = rintf(-mn / scale);
  u16x4 o4;
  o4[0] = f2bf((fminf(fmaxf(rintf(x.x / scale) + zero, 0.f), 255.f) - zero) * scale);
  o4[1] = f2bf((fminf(fmaxf(rintf(x.y / scale) + zero, 0.f), 255.f) - zero) * scale);
  o4[2] = f2bf((fminf(fmaxf(rintf(x.z / scale) + zero, 0.f), 255.f) - zero) * scale);
  o4[3] = f2bf((fminf(fmaxf(rintf(x.w / scale) + zero, 0.f), 255.f) - zero) * scale);
  ((u16x4*)vTb)[(size_t)blockIdx.x * 256 + t] = o4;
}

// ---------------------------------------------------------------------------
extern "C" void kernel_launch(void* const* d_in, const int* in_sizes, int n_in,
                              void* d_out, int out_size, void* d_ws, size_t ws_size,
                              hipStream_t stream) {
  const float* hs = (const float*)d_in[0];
  const float* cosp = (const float*)d_in[1];
  const float* sinp = (const float*)d_in[2];
  const float* Wq = (const float*)d_in[4];
  const float* Wk = (const float*)d_in[5];
  const float* Wv = (const float*)d_in[6];
  const float* Wo = (const float*)d_in[7];

  float* out = (float*)d_out;
  float* wout = out + (size_t)Bb * Ss * HID;  // w output region (fp32)

  char* wsp = (char*)d_ws;
  auto alloc = [&](size_t bytes) {
    char* p = wsp;
    wsp += (bytes + 255) & ~(size_t)255;
    return p;
  };
  float* q     = (float*)alloc((size_t)Bb * NH * Ss * HD * 4);   // 33.6 MB
  float* k     = (float*)alloc((size_t)Bb * NKV * Ss * HD * 4);  // 8.4 MB
  float* vT    = (float*)alloc((size_t)Bb * NKV * Ss * HD * 4);  // 8.4 MB
  float* kmean = (float*)alloc((size_t)Bb * NKV * HD * 4);
  u16* hsb = (u16*)alloc((size_t)Bb * Ss * HID * 2);
  u16* qb  = (u16*)alloc((size_t)Bb * NH * Ss * HD * 2);
  u16* kb  = (u16*)alloc((size_t)Bb * NKV * Ss * HD * 2);
  u16* vTb = (u16*)alloc((size_t)Bb * NKV * Ss * HD * 2);
  u16* Wqb = (u16*)alloc((size_t)NH * HD * HID * 2);
  u16* Wkb = (u16*)alloc((size_t)NKV * HD * HID * 2);
  u16* Wvb = (u16*)alloc((size_t)NKV * HD * HID * 2);
  u16* Wob = (u16*)alloc((size_t)HID * NH * HD * 2);
  u16* attnb = (u16*)q;  // q fp32 dead after rope_quant_q; reuse

  // fp32 -> bf16 conversions
  f32_to_bf16_k<<<(Bb * Ss * HID / 8 + 255) / 256, 256, 0, stream>>>(hs, hsb, Bb * Ss * HID / 8);
  f32_to_bf16_k<<<(NH * HD * HID / 8 + 255) / 256, 256, 0, stream>>>(Wq, Wqb, NH * HD * HID / 8);
  f32_to_bf16_k<<<(NKV * HD * HID / 8 + 255) / 256, 256, 0, stream>>>(Wk, Wkb, NKV * HD * HID / 8);
  f32_to_bf16_k<<<(NKV * HD * HID / 8 + 255) / 256, 256, 0, stream>>>(Wv, Wvb, NKV * HD * HID / 8);
  f32_to_bf16_k<<<(HID * NH * HD / 8 + 255) / 256, 256, 0, stream>>>(Wo, Wob, HID * NH * HD / 8);

  // fused Q/K/V projection
  mfma_gemm<M_QKV><<<dim3(48, 16, 1), 256, 0, stream>>>(
      hsb, Wqb, Wkb, Wvb, q, k, vT, HID);

  // RoPE / mean-center / quantize
  rope_quant_q<<<(Bb * NH * Ss) / 4, 256, 0, stream>>>(q, qb, cosp, sinp);
  rope_k<<<(Bb * NKV * Ss) / 4, 256, 0, stream>>>(k, cosp, sinp);
  kmean_kernel<<<Bb * NKV, 1024, 0, stream>>>(k, kmean);
  k_subquant<<<(Bb * NKV * Ss) / 4, 256, 0, stream>>>(k, kb, kmean);
  vquant<<<Bb * NKV * HD, 256, 0, stream>>>(vT, vTb);

  // fused scores+softmax+quant(w)+PV  (1024 uniform-work blocks, heavy first)
  fused_attn<<<dim3(1024), 256, 0, stream>>>(qb, kb, vTb, wout, attnb);

  // out = attn @ Wo^T (fp32 out)
  mfma_gemm<M_OUT><<<dim3(32, 16, 1), 256, 0, stream>>>(
      attnb, Wob, nullptr, nullptr, out, nullptr, nullptr, HID);
}

// Round 5
// 453.945 us; speedup vs baseline: 1.5065x; 1.1229x over previous
//
#include <hip/hip_runtime.h>
#include <math.h>
#include <stdint.h>

typedef unsigned int u32;
typedef unsigned short u16;
typedef __bf16 bf16x8 __attribute__((ext_vector_type(8)));
typedef float f32x4 __attribute__((ext_vector_type(4)));
typedef unsigned short u16x8 __attribute__((ext_vector_type(8)));
typedef unsigned short u16x4 __attribute__((ext_vector_type(4)));

constexpr int   Bb  = 2;
constexpr int   Ss  = 1024;
constexpr int   HID = 4096;
constexpr int   NH  = 32;
constexpr int   NKV = 8;
constexpr int   HD  = 128;
constexpr float SCALING = 0.0883883476483184405501f; // 128^-0.5

enum { M_QKV = 0, M_OUT = 3 };

// fp32 -> bf16 RTNE (bit trick; finite values only here)
__device__ __forceinline__ u16 f2bf(float f) {
  u32 u = __builtin_bit_cast(u32, f);
  u = u + 0x7fffu + ((u >> 16) & 1u);
  return (u16)(u >> 16);
}

// async global->LDS, 16B per lane; LDS dest = wave-uniform base (+ lane*16 by HW)
__device__ __forceinline__ void gld_lds16(const void* g, void* l) {
  __builtin_amdgcn_global_load_lds(
      (const __attribute__((address_space(1))) u32*)(uintptr_t)g,
      (__attribute__((address_space(3))) u32*)(uintptr_t)l, 16, 0, 0);
}

// ---------------------------------------------------------------------------
// bf16 MFMA GEMM, 128x128 tile, BK=32, 4 waves (2x2), 16x16x32 MFMA.
// Pipelined K-loop: triple-buffered LDS, stage tile kt+2 each iter, raw
// s_barrier + counted s_waitcnt vmcnt(4) (loads stay in flight across
// barriers; tile kt+1 guaranteed landed before its reads).
// ---------------------------------------------------------------------------
template <int MODE>
__global__ __launch_bounds__(256, 3) void mfma_gemm(
    const u16* __restrict__ Abf_g,
    const u16* __restrict__ B0, const u16* __restrict__ B1,
    const u16* __restrict__ B2,
    float* __restrict__ Cf, float* __restrict__ Ck, float* __restrict__ Cv,
    int K) {
  __shared__ u16 As[3][128 * 32];  // 3 x 8 KB
  __shared__ u16 Bs[3][128 * 32];  // 3 x 8 KB

  const int tid = threadIdx.x;
  const int lane = tid & 63;
  const int wid = tid >> 6;
  const int wr = wid >> 1, wc = wid & 1;

  const int m0 = blockIdx.y * 128;
  int nloc = blockIdx.x * 128;

  const u16* Abf = Abf_g + (size_t)m0 * K;
  const u16* Bp = nullptr;
  int which = 0;

  if (MODE == M_QKV) {
    const int j = blockIdx.x;  // 0..47: 32 Q col-blocks, 8 K, 8 V
    if (j < 32)      { which = 0; Bp = B0 + (size_t)j * 128 * K;        nloc = j * 128; }
    else if (j < 40) { which = 1; Bp = B1 + (size_t)(j - 32) * 128 * K; nloc = (j - 32) * 128; }
    else             { which = 2; Bp = B2 + (size_t)(j - 40) * 128 * K; nloc = (j - 40) * 128; }
  } else {  // M_OUT
    Bp = B0 + (size_t)nloc * K;
  }

  f32x4 acc[4][4];
#pragma unroll
  for (int i = 0; i < 4; i++)
#pragma unroll
    for (int j = 0; j < 4; j++) acc[i][j] = (f32x4){0.f, 0.f, 0.f, 0.f};

  const int sr = lane >> 2;  // row within 16-row chunk
  const int sp = lane & 3;   // 16B slot within 64B row
  const int fr = lane & 15;
  const int fq = lane >> 4;

  const int nk = K >> 5;  // K / 32

  // prologue: stage tiles 0 and 1
#pragma unroll
  for (int p = 0; p < 2; ++p) {
#pragma unroll
    for (int cc = 0; cc < 2; ++cc) {
      const int c = wid + cc * 4;
      const int r = c * 16 + sr;
      const int go = (sp ^ ((r >> 1) & 3)) * 8;
      gld_lds16(Abf + (size_t)r * K + p * 32 + go, &As[p][c * 512]);
      gld_lds16(Bp + (size_t)r * K + p * 32 + go, &Bs[p][c * 512]);
    }
  }
  asm volatile("s_waitcnt vmcnt(4)" ::: "memory");  // tile 0 landed
  __builtin_amdgcn_sched_barrier(0);
  __builtin_amdgcn_s_barrier();

  int cur = 0;
  for (int kt = 0; kt < nk; ++kt) {
    // stage tile kt+2 into buf (kt+2)%3 == (kt-1)%3 (read finished at iter kt-1)
    if (kt + 2 < nk) {
      const int stg = (cur == 0) ? 2 : cur - 1;
#pragma unroll
      for (int cc = 0; cc < 2; ++cc) {
        const int c = wid + cc * 4;
        const int r = c * 16 + sr;
        const int go = (sp ^ ((r >> 1) & 3)) * 8;
        gld_lds16(Abf + (size_t)r * K + (kt + 2) * 32 + go, &As[stg][c * 512]);
        gld_lds16(Bp + (size_t)r * K + (kt + 2) * 32 + go, &Bs[stg][c * 512]);
      }
    }

    bf16x8 av[4], bv[4];
#pragma unroll
    for (int f = 0; f < 4; ++f) {
      const int ra = wr * 64 + f * 16 + fr;
      av[f] = *(const bf16x8*)&As[cur][ra * 32 + ((fq ^ ((ra >> 1) & 3)) * 8)];
      const int rb = wc * 64 + f * 16 + fr;
      bv[f] = *(const bf16x8*)&Bs[cur][rb * 32 + ((fq ^ ((rb >> 1) & 3)) * 8)];
    }

    __builtin_amdgcn_s_setprio(1);
#pragma unroll
    for (int i = 0; i < 4; i++)
#pragma unroll
      for (int j = 0; j < 4; j++)
        acc[i][j] = __builtin_amdgcn_mfma_f32_16x16x32_bf16(av[i], bv[j], acc[i][j], 0, 0, 0);
    __builtin_amdgcn_s_setprio(0);

    // tile kt+1 landed; leave tile kt+2's 4 loads in flight
    if (kt + 2 < nk) {
      asm volatile("s_waitcnt vmcnt(4)" ::: "memory");
    } else {
      asm volatile("s_waitcnt vmcnt(0)" ::: "memory");
    }
    __builtin_amdgcn_sched_barrier(0);
    __builtin_amdgcn_s_barrier();
    cur = (cur == 2) ? 0 : cur + 1;
  }

#pragma unroll
  for (int i = 0; i < 4; i++) {
#pragma unroll
    for (int j = 0; j < 4; j++) {
      const int n = nloc + wc * 64 + j * 16 + fr;
#pragma unroll
      for (int e = 0; e < 4; e++) {
        const int m = m0 + wr * 64 + i * 16 + fq * 4 + e;
        float val = acc[i][j][e];
        if (MODE == M_QKV) {
          const int b = m >> 10, s = m & 1023, h = n >> 7, d = n & 127;
          if (which == 0)      Cf[((size_t)(b * NH + h) * Ss + s) * HD + d] = val;
          else if (which == 1) Ck[((size_t)(b * NKV + h) * Ss + s) * HD + d] = val;
          else                 Cv[((size_t)(b * NKV + h) * HD + d) * Ss + s] = val;
        } else {  // M_OUT
          Cf[(size_t)m * HID + n] = val;
        }
      }
    }
  }
}

// ---------------------------------------------------------------------------
// Fused causal attention, block-cooperative (unchanged from R4):
//   block = (a, bh): 64 q-rows, 4 waves x 16 rows, nt = a+1 k-tiles.
// ---------------------------------------------------------------------------
__global__ __launch_bounds__(256) void fused_attn(
    const u16* __restrict__ qb,   // [B*NH*S][128]
    const u16* __restrict__ kb,   // [B*NKV*S][128]
    const u16* __restrict__ vTb,  // [B*NKV][128][1024]
    float* __restrict__ wout,     // [B*NH][1024][1024]
    u16* __restrict__ attnb) {    // [B*S][4096]
  __shared__ u16 Ks[64 * 128];
  __shared__ u16 Vs[128 * 64];
  __shared__ u16 plds[4][16 * 64];
  __shared__ float scl_l[4][16];

  const int a = 15 - (int)(blockIdx.x >> 6);  // heavy blocks first
  const int bh = blockIdx.x & 63;
  const int b = bh >> 5, h = bh & 31;
  const int kv = h >> 2;
  const int tid = threadIdx.x;
  const int lane = tid & 63;
  const int wq = tid >> 6;
  const int fr = lane & 15, fq = lane >> 4;

  const int nt = a + 1;
  const int Q0 = a * 64;
  const int qw0 = Q0 + wq * 16;

  const u16* Kb = kb + (size_t)(b * NKV + kv) * Ss * HD;
  const u16* Vb = vTb + (size_t)(b * NKV + kv) * HD * Ss;
  float* wrow = wout + (size_t)bh * Ss * Ss;

  // zero-fill fully-masked columns [nt*64, 1024)
  if (a < 15) {
    const int base = 64 * nt;
    const int n4 = 16 * (15 - a);
#pragma unroll
    for (int r0 = 0; r0 < 4; ++r0) {
      const int row = Q0 + r0 * 16 + (tid >> 4);
      float4* wp = (float4*)&wrow[(size_t)row * Ss + base];
      for (int c = tid & 15; c < n4; c += 16) wp[c] = float4{0.f, 0.f, 0.f, 0.f};
    }
  }

  // Q fragments (reused by both sweeps)
  bf16x8 qf[4];
#pragma unroll
  for (int kk = 0; kk < 4; kk++)
    qf[kk] = *(const bf16x8*)&qb[((size_t)bh * Ss + qw0 + fr) * HD + kk * 32 + fq * 8];

  // ================= sweep 1: online m, l =================
  float m[4], l[4];
#pragma unroll
  for (int i = 0; i < 4; i++) { m[i] = -1e30f; l[i] = 0.f; }

  for (int t = 0; t < nt; ++t) {
    __syncthreads();
#pragma unroll
    for (int c = 0; c < 4; ++c) {
      const int idx0 = (c * 4 + wq) * 64;
      const int idx = idx0 + lane;
      const int row = idx >> 4, sl = idx & 15;
      const int slot = sl ^ (row & 15);
      gld_lds16(Kb + (size_t)(t * 64 + row) * HD + slot * 8, &Ks[idx0 * 8]);
    }
    __syncthreads();

    f32x4 sa[4];
#pragma unroll
    for (int jn = 0; jn < 4; jn++) sa[jn] = (f32x4){0.f, 0.f, 0.f, 0.f};
#pragma unroll
    for (int kk = 0; kk < 4; ++kk) {
      bf16x8 kfv[4];
#pragma unroll
      for (int jn = 0; jn < 4; ++jn) {
        const int row = jn * 16 + fr;
        kfv[jn] = *(const bf16x8*)&Ks[row * 128 + (((kk * 4 + fq) ^ fr) * 8)];
      }
#pragma unroll
      for (int jn = 0; jn < 4; ++jn)
        sa[jn] = __builtin_amdgcn_mfma_f32_16x16x32_bf16(qf[kk], kfv[jn], sa[jn], 0, 0, 0);
    }

    const bool diag = (t == a);
#pragma unroll
    for (int e = 0; e < 4; ++e) {
      const int qrow = qw0 + fq * 4 + e;
      float sv[4];
      float rmax = -1e30f;
#pragma unroll
      for (int jn = 0; jn < 4; ++jn) {
        float s = sa[jn][e] * SCALING;
        if (diag && (t * 64 + jn * 16 + fr > qrow)) s = -1e30f;
        sv[jn] = s;
        rmax = fmaxf(rmax, s);
      }
#pragma unroll
      for (int o = 1; o < 16; o <<= 1) rmax = fmaxf(rmax, __shfl_xor(rmax, o));
      const float mn = fmaxf(m[e], rmax);
      const float cc = __expf(m[e] - mn);
      float rs = __expf(sv[0] - mn) + __expf(sv[1] - mn) +
                 __expf(sv[2] - mn) + __expf(sv[3] - mn);
#pragma unroll
      for (int o = 1; o < 16; o <<= 1) rs += __shfl_xor(rs, o);
      l[e] = l[e] * cc + rs;
      m[e] = mn;
    }
  }

  float scl[4];
#pragma unroll
  for (int e = 0; e < 4; e++) scl[e] = 1.f / (255.f * l[e]);
  if (fr == 0) {
#pragma unroll
    for (int e = 0; e < 4; e++) scl_l[wq][fq * 4 + e] = scl[e];
  }

  // ================= sweep 2: emit w + PV =================
  f32x4 acc2[8];
#pragma unroll
  for (int j = 0; j < 8; j++) acc2[j] = (f32x4){0.f, 0.f, 0.f, 0.f};

  u16* pl = &plds[wq][0];
  const int wrrow = lane >> 2, wrq = lane & 3;
  const float sclr = scl_l[wq][wrrow];

  for (int t = 0; t < nt; ++t) {
    __syncthreads();
#pragma unroll
    for (int c = 0; c < 4; ++c) {
      const int idx0 = (c * 4 + wq) * 64;
      const int idx = idx0 + lane;
      {
        const int row = idx >> 4, sl = idx & 15;
        const int slot = sl ^ (row & 15);
        gld_lds16(Kb + (size_t)(t * 64 + row) * HD + slot * 8, &Ks[idx0 * 8]);
      }
      {
        const int d = idx >> 3, sl = idx & 7;
        const int slot = sl ^ (d & 7);
        gld_lds16(Vb + (size_t)d * Ss + t * 64 + slot * 8, &Vs[idx0 * 8]);
      }
    }
    __syncthreads();

    f32x4 sa[4];
#pragma unroll
    for (int jn = 0; jn < 4; jn++) sa[jn] = (f32x4){0.f, 0.f, 0.f, 0.f};
#pragma unroll
    for (int kk = 0; kk < 4; ++kk) {
      bf16x8 kfv[4];
#pragma unroll
      for (int jn = 0; jn < 4; ++jn) {
        const int row = jn * 16 + fr;
        kfv[jn] = *(const bf16x8*)&Ks[row * 128 + (((kk * 4 + fq) ^ fr) * 8)];
      }
#pragma unroll
      for (int jn = 0; jn < 4; ++jn)
        sa[jn] = __builtin_amdgcn_mfma_f32_16x16x32_bf16(qf[kk], kfv[jn], sa[jn], 0, 0, 0);
    }

    const bool diag = (t == a);
#pragma unroll
    for (int e = 0; e < 4; ++e) {
      const int qrow = qw0 + fq * 4 + e;
      const int r16 = fq * 4 + e;
#pragma unroll
      for (int jn = 0; jn < 4; ++jn) {
        const int kc = t * 64 + jn * 16 + fr;
        float qv = 0.f;
        if (!diag || kc <= qrow)
          qv = rintf(fminf(255.f * __expf(sa[jn][e] * SCALING - m[e]), 255.f));
        const int col = jn * 16 + fr;
        const int byte = r16 * 128 + (((col >> 3) ^ (r16 & 7)) * 16) + (col & 7) * 2;
        *(u16*)((char*)pl + byte) = f2bf(qv);
      }
    }

    // vectorized w write
    {
      const int s0 = (2 * wrq) ^ (wrrow & 7);
      const int s1 = (2 * wrq + 1) ^ (wrrow & 7);
      bf16x8 p0 = *(const bf16x8*)((char*)pl + wrrow * 128 + s0 * 16);
      bf16x8 p1 = *(const bf16x8*)((char*)pl + wrrow * 128 + s1 * 16);
      float* wp = &wrow[(size_t)(qw0 + wrrow) * Ss + t * 64 + wrq * 16];
      float4 o0, o1, o2, o3;
      o0.x = (float)p0[0] * sclr; o0.y = (float)p0[1] * sclr;
      o0.z = (float)p0[2] * sclr; o0.w = (float)p0[3] * sclr;
      o1.x = (float)p0[4] * sclr; o1.y = (float)p0[5] * sclr;
      o1.z = (float)p0[6] * sclr; o1.w = (float)p0[7] * sclr;
      o2.x = (float)p1[0] * sclr; o2.y = (float)p1[1] * sclr;
      o2.z = (float)p1[2] * sclr; o2.w = (float)p1[3] * sclr;
      o3.x = (float)p1[4] * sclr; o3.y = (float)p1[5] * sclr;
      o3.z = (float)p1[6] * sclr; o3.w = (float)p1[7] * sclr;
      ((float4*)wp)[0] = o0; ((float4*)wp)[1] = o1;
      ((float4*)wp)[2] = o2; ((float4*)wp)[3] = o3;
    }

    // PV
#pragma unroll
    for (int kk2 = 0; kk2 < 2; ++kk2) {
      const bf16x8 pa = *(const bf16x8*)((char*)pl + fr * 128 + (((kk2 * 4 + fq) ^ (fr & 7)) * 16));
#pragma unroll
      for (int jn2 = 0; jn2 < 8; ++jn2) {
        const int d = jn2 * 16 + fr;
        const bf16x8 vb = *(const bf16x8*)&Vs[d * 64 + (((kk2 * 4 + fq) ^ (d & 7)) * 8)];
        acc2[jn2] = __builtin_amdgcn_mfma_f32_16x16x32_bf16(pa, vb, acc2[jn2], 0, 0, 0);
      }
    }
  }

  // epilogue: attn -> bf16 [B*S][NH*HD]
#pragma unroll
  for (int e = 0; e < 4; ++e) {
    const int qrow = qw0 + fq * 4 + e;
#pragma unroll
    for (int jn2 = 0; jn2 < 8; ++jn2)
      attnb[((size_t)b * Ss + qrow) * HID + h * HD + jn2 * 16 + fr] =
          f2bf(acc2[jn2][e] * scl[e]);
  }
}

// ---------------------------------------------------------------------------
// fp32 -> bf16 conversion, 8 elems/thread
__global__ __launch_bounds__(256) void f32_to_bf16_k(const float* __restrict__ in,
                                                     u16* __restrict__ out, int n8) {
  const int i = blockIdx.x * 256 + threadIdx.x;
  if (i < n8) {
    float4 a = ((const float4*)in)[2 * i];
    float4 b = ((const float4*)in)[2 * i + 1];
    u16x8 t;
    t[0] = f2bf(a.x); t[1] = f2bf(a.y); t[2] = f2bf(a.z); t[3] = f2bf(a.w);
    t[4] = f2bf(b.x); t[5] = f2bf(b.y); t[6] = f2bf(b.z); t[7] = f2bf(b.w);
    ((u16x8*)out)[i] = t;
  }
}

// RoPE + per-row asymmetric 8-bit fake-quant for q -> bf16. One wave per row.
__global__ __launch_bounds__(256) void rope_quant_q(const float* __restrict__ q,
                                                    u16* __restrict__ qb,
                                                    const float* __restrict__ cs,
                                                    const float* __restrict__ sn) {
  const int row = blockIdx.x * 4 + (threadIdx.x >> 6);
  const int lane = threadIdx.x & 63;
  const int s = row & (Ss - 1);
  const int b = row >> 15;
  const float* p = q + (size_t)row * HD;
  const float* cp = cs + ((size_t)b * Ss + s) * HD;
  const float* sp = sn + ((size_t)b * Ss + s) * HD;
  float x1 = p[lane], x2 = p[lane + 64];
  float r1 = x1 * cp[lane] - x2 * sp[lane];
  float r2 = x2 * cp[lane + 64] + x1 * sp[lane + 64];
  float mn = fminf(0.f, fminf(r1, r2));
  float mx = fmaxf(0.f, fmaxf(r1, r2));
#pragma unroll
  for (int o = 32; o; o >>= 1) {
    mn = fminf(mn, __shfl_xor(mn, o));
    mx = fmaxf(mx, __shfl_xor(mx, o));
  }
  float rng = mx - mn;
  float scale = (rng == 0.f) ? 1.f : rng / 255.f;
  float zero = rintf(-mn / scale);
  float q1 = fminf(fmaxf(rintf(r1 / scale) + zero, 0.f), 255.f);
  float q2 = fminf(fmaxf(rintf(r2 / scale) + zero, 0.f), 255.f);
  qb[(size_t)row * HD + lane] = f2bf((q1 - zero) * scale);
  qb[(size_t)row * HD + lane + 64] = f2bf((q2 - zero) * scale);
}

// RoPE only for k. One wave per row, in place.
__global__ __launch_bounds__(256) void rope_k(float* __restrict__ k,
                                              const float* __restrict__ cs,
                                              const float* __restrict__ sn) {
  const int row = blockIdx.x * 4 + (threadIdx.x >> 6);
  const int lane = threadIdx.x & 63;
  const int s = row & (Ss - 1);
  const int b = row >> 13;
  float* p = k + (size_t)row * HD;
  const float* cp = cs + ((size_t)b * Ss + s) * HD;
  const float* sp = sn + ((size_t)b * Ss + s) * HD;
  float x1 = p[lane], x2 = p[lane + 64];
  float r1 = x1 * cp[lane] - x2 * sp[lane];
  float r2 = x2 * cp[lane + 64] + x1 * sp[lane + 64];
  p[lane] = r1;
  p[lane + 64] = r2;
}

// Mean of k over S per (b,h,d). One 1024-thread block per (b,h).
__global__ __launch_bounds__(1024) void kmean_kernel(const float* __restrict__ k,
                                                     float* __restrict__ kmean) {
  const int bh = blockIdx.x;
  const int d = threadIdx.x & 127;
  const int sl = threadIdx.x >> 7;
  const float* p = k + (size_t)bh * Ss * HD;
  float sum = 0.f;
  for (int s = sl; s < Ss; s += 8) sum += p[(size_t)s * HD + d];
  __shared__ float lds[8][128];
  lds[sl][d] = sum;
  __syncthreads();
  if (threadIdx.x < 128) {
    float t = 0.f;
#pragma unroll
    for (int i = 0; i < 8; i++) t += lds[i][threadIdx.x];
    kmean[bh * HD + threadIdx.x] = t * (1.f / 1024.f);
  }
}

// Subtract mean + per-row quant for k -> bf16. One wave per row.
__global__ __launch_bounds__(256) void k_subquant(const float* __restrict__ k,
                                                  u16* __restrict__ kb,
                                                  const float* __restrict__ kmean) {
  const int row = blockIdx.x * 4 + (threadIdx.x >> 6);
  const int lane = threadIdx.x & 63;
  const int bh = row >> 10;
  const float* p = k + (size_t)row * HD;
  float x1 = p[lane] - kmean[bh * HD + lane];
  float x2 = p[lane + 64] - kmean[bh * HD + lane + 64];
  float mn = fminf(0.f, fminf(x1, x2));
  float mx = fmaxf(0.f, fmaxf(x1, x2));
#pragma unroll
  for (int o = 32; o; o >>= 1) {
    mn = fminf(mn, __shfl_xor(mn, o));
    mx = fmaxf(mx, __shfl_xor(mx, o));
  }
  float rng = mx - mn;
  float scale = (rng == 0.f) ? 1.f : rng / 255.f;
  float zero = rintf(-mn / scale);
  float q1 = fminf(fmaxf(rintf(x1 / scale) + zero, 0.f), 255.f);
  float q2 = fminf(fmaxf(rintf(x2 / scale) + zero, 0.f), 255.f);
  kb[(size_t)row * HD + lane] = f2bf((q1 - zero) * scale);
  kb[(size_t)row * HD + lane + 64] = f2bf((q2 - zero) * scale);
}

// Per-(b,h,d) quant of v over S (vT rows) -> bf16. One block per row.
__global__ __launch_bounds__(256) void vquant(const float* __restrict__ vT,
                                              u16* __restrict__ vTb) {
  const float* p = vT + (size_t)blockIdx.x * Ss;
  const int t = threadIdx.x;
  float4 x = ((const float4*)p)[t];
  float mn = fminf(0.f, fminf(fminf(x.x, x.y), fminf(x.z, x.w)));
  float mx = fmaxf(0.f, fmaxf(fmaxf(x.x, x.y), fmaxf(x.z, x.w)));
#pragma unroll
  for (int o = 32; o; o >>= 1) {
    mn = fminf(mn, __shfl_xor(mn, o));
    mx = fmaxf(mx, __shfl_xor(mx, o));
  }
  __shared__ float smn[4], smx[4];
  const int wid = t >> 6, lane = t & 63;
  if (lane == 0) { smn[wid] = mn; smx[wid] = mx; }
  __syncthreads();
  mn = fminf(fminf(smn[0], smn[1]), fminf(smn[2], smn[3]));
  mx = fmaxf(fmaxf(smx[0], smx[1]), fmaxf(smx[2], smx[3]));
  float rng = mx - mn;
  float scale = (rng == 0.f) ? 1.f : rng / 255.f;
  float zero = rintf(-mn / scale);
  u16x4 o4;
  o4[0] = f2bf((fminf(fmaxf(rintf(x.x / scale) + zero, 0.f), 255.f) - zero) * scale);
  o4[1] = f2bf((fminf(fmaxf(rintf(x.y / scale) + zero, 0.f), 255.f) - zero) * scale);
  o4[2] = f2bf((fminf(fmaxf(rintf(x.z / scale) + zero, 0.f), 255.f) - zero) * scale);
  o4[3] = f2bf((fminf(fmaxf(rintf(x.w / scale) + zero, 0.f), 255.f) - zero) * scale);
  ((u16x4*)vTb)[(size_t)blockIdx.x * 256 + t] = o4;
}

// ---------------------------------------------------------------------------
extern "C" void kernel_launch(void* const* d_in, const int* in_sizes, int n_in,
                              void* d_out, int out_size, void* d_ws, size_t ws_size,
                              hipStream_t stream) {
  const float* hs = (const float*)d_in[0];
  const float* cosp = (const float*)d_in[1];
  const float* sinp = (const float*)d_in[2];
  const float* Wq = (const float*)d_in[4];
  const float* Wk = (const float*)d_in[5];
  const float* Wv = (const float*)d_in[6];
  const float* Wo = (const float*)d_in[7];

  float* out = (float*)d_out;
  float* wout = out + (size_t)Bb * Ss * HID;  // w output region (fp32)

  char* wsp = (char*)d_ws;
  auto alloc = [&](size_t bytes) {
    char* p = wsp;
    wsp += (bytes + 255) & ~(size_t)255;
    return p;
  };
  float* q     = (float*)alloc((size_t)Bb * NH * Ss * HD * 4);   // 33.6 MB
  float* k     = (float*)alloc((size_t)Bb * NKV * Ss * HD * 4);  // 8.4 MB
  float* vT    = (float*)alloc((size_t)Bb * NKV * Ss * HD * 4);  // 8.4 MB
  float* kmean = (float*)alloc((size_t)Bb * NKV * HD * 4);
  u16* hsb = (u16*)alloc((size_t)Bb * Ss * HID * 2);
  u16* qb  = (u16*)alloc((size_t)Bb * NH * Ss * HD * 2);
  u16* kb  = (u16*)alloc((size_t)Bb * NKV * Ss * HD * 2);
  u16* vTb = (u16*)alloc((size_t)Bb * NKV * Ss * HD * 2);
  u16* Wqb = (u16*)alloc((size_t)NH * HD * HID * 2);
  u16* Wkb = (u16*)alloc((size_t)NKV * HD * HID * 2);
  u16* Wvb = (u16*)alloc((size_t)NKV * HD * HID * 2);
  u16* Wob = (u16*)alloc((size_t)HID * NH * HD * 2);
  u16* attnb = (u16*)q;  // q fp32 dead after rope_quant_q; reuse

  // fp32 -> bf16 conversions
  f32_to_bf16_k<<<(Bb * Ss * HID / 8 + 255) / 256, 256, 0, stream>>>(hs, hsb, Bb * Ss * HID / 8);
  f32_to_bf16_k<<<(NH * HD * HID / 8 + 255) / 256, 256, 0, stream>>>(Wq, Wqb, NH * HD * HID / 8);
  f32_to_bf16_k<<<(NKV * HD * HID / 8 + 255) / 256, 256, 0, stream>>>(Wk, Wkb, NKV * HD * HID / 8);
  f32_to_bf16_k<<<(NKV * HD * HID / 8 + 255) / 256, 256, 0, stream>>>(Wv, Wvb, NKV * HD * HID / 8);
  f32_to_bf16_k<<<(HID * NH * HD / 8 + 255) / 256, 256, 0, stream>>>(Wo, Wob, HID * NH * HD / 8);

  // fused Q/K/V projection
  mfma_gemm<M_QKV><<<dim3(48, 16, 1), 256, 0, stream>>>(
      hsb, Wqb, Wkb, Wvb, q, k, vT, HID);

  // RoPE / mean-center / quantize
  rope_quant_q<<<(Bb * NH * Ss) / 4, 256, 0, stream>>>(q, qb, cosp, sinp);
  rope_k<<<(Bb * NKV * Ss) / 4, 256, 0, stream>>>(k, cosp, sinp);
  kmean_kernel<<<Bb * NKV, 1024, 0, stream>>>(k, kmean);
  k_subquant<<<(Bb * NKV * Ss) / 4, 256, 0, stream>>>(k, kb, kmean);
  vquant<<<Bb * NKV * HD, 256, 0, stream>>>(vT, vTb);

  // fused scores+softmax+quant(w)+PV  (1024 uniform-work blocks, heavy first)
  fused_attn<<<dim3(1024), 256, 0, stream>>>(qb, kb, vTb, wout, attnb);

  // out = attn @ Wo^T (fp32 out)
  mfma_gemm<M_OUT><<<dim3(32, 16, 1), 256, 0, stream>>>(
      attnb, Wob, nullptr, nullptr, out, nullptr, nullptr, HID);
}

// Round 6
// 446.560 us; speedup vs baseline: 1.5315x; 1.0165x over previous
//
#include <hip/hip_runtime.h>
#include <math.h>
#include <stdint.h>

typedef unsigned int u32;
typedef unsigned short u16;
typedef __bf16 bf16x8 __attribute__((ext_vector_type(8)));
typedef float f32x4 __attribute__((ext_vector_type(4)));
typedef unsigned short u16x8 __attribute__((ext_vector_type(8)));
typedef unsigned short u16x4 __attribute__((ext_vector_type(4)));

constexpr int   Bb  = 2;
constexpr int   Ss  = 1024;
constexpr int   HID = 4096;
constexpr int   NH  = 32;
constexpr int   NKV = 8;
constexpr int   HD  = 128;
constexpr float SCALING = 0.0883883476483184405501f; // 128^-0.5

enum { M_QKV = 0, M_OUT = 3 };

// fp32 -> bf16 RTNE (bit trick; finite values only here)
__device__ __forceinline__ u16 f2bf(float f) {
  u32 u = __builtin_bit_cast(u32, f);
  u = u + 0x7fffu + ((u >> 16) & 1u);
  return (u16)(u >> 16);
}

// async global->LDS, 16B per lane; LDS dest = wave-uniform base (+ lane*16 by HW)
__device__ __forceinline__ void gld_lds16(const void* g, void* l) {
  __builtin_amdgcn_global_load_lds(
      (const __attribute__((address_space(1))) u32*)(uintptr_t)g,
      (__attribute__((address_space(3))) u32*)(uintptr_t)l, 16, 0, 0);
}

// ---------------------------------------------------------------------------
// bf16 MFMA GEMM, 256 x (NREP*64) tile, BK=32, 512 threads (8 waves, 2Mx4N),
// wave tile 128 x (NREP*16). 4-buffer LDS pipeline: step kt reads buf[kt&3],
// stages tile kt+3 into buf[(kt+3)&3] (last read at step kt-1 -> race-free).
// Counted vmcnt leaves 2 tiles (2*LPW loads) in flight across barriers.
// ---------------------------------------------------------------------------
template <int MODE, int NREP>
__global__ __launch_bounds__(512) void mfma_gemm(
    const u16* __restrict__ Abf_g,
    const u16* __restrict__ B0, const u16* __restrict__ B1,
    const u16* __restrict__ B2,
    float* __restrict__ Cf, float* __restrict__ Ck, float* __restrict__ Cv,
    int K) {
  constexpr int BN = NREP * 64;
  constexpr int BCW = BN / 128;  // B chunks per wave (2 or 1)
  __shared__ u16 As[4][256 * 32];  // 4 x 16 KB
  __shared__ u16 Bs[4][BN * 32];   // 4 x (16 | 8) KB

  const int tid = threadIdx.x;
  const int lane = tid & 63;
  const int wid = tid >> 6;        // 0..7
  const int wr = wid >> 2;         // 0..1
  const int wc = wid & 3;          // 0..3

  const int m0 = blockIdx.y * 256;
  int nloc = 0;

  const u16* Abf = Abf_g + (size_t)m0 * K;
  const u16* Bp = nullptr;
  int which = 0;

  if (MODE == M_QKV) {
    const int j = blockIdx.x;  // 0..23: 16 Q col-blocks, 4 K, 4 V
    if (j < 16)      { which = 0; Bp = B0 + (size_t)j * 256 * K;        nloc = j * 256; }
    else if (j < 20) { which = 1; Bp = B1 + (size_t)(j - 16) * 256 * K; nloc = (j - 16) * 256; }
    else             { which = 2; Bp = B2 + (size_t)(j - 20) * 256 * K; nloc = (j - 20) * 256; }
  } else {  // M_OUT
    Bp = B0 + (size_t)blockIdx.x * BN * K;
    nloc = blockIdx.x * BN;
  }

  f32x4 acc[8][NREP];
#pragma unroll
  for (int i = 0; i < 8; i++)
#pragma unroll
    for (int j = 0; j < NREP; j++) acc[i][j] = (f32x4){0.f, 0.f, 0.f, 0.f};

  const int fr = lane & 15;
  const int fq = lane >> 4;
  const int srow = lane >> 2;  // staging: row within 16-row chunk
  const int ssl = lane & 3;    // staging: 16B slot

  const int nk = K >> 5;

  // stage tile t (BK=32 cols) into buffer sbuf
  auto stage = [&](int t, int sbuf) {
    const int ko = t * 32;
#pragma unroll
    for (int cc = 0; cc < 2; ++cc) {  // A: chunks 2w, 2w+1 (256 rows total)
      const int c = wid * 2 + cc;
      const int r = c * 16 + srow;
      gld_lds16(Abf + (size_t)r * K + ko + ((ssl ^ ((r >> 1) & 3)) * 8),
                &As[sbuf][c * 512]);
    }
#pragma unroll
    for (int cc = 0; cc < BCW; ++cc) {  // B: BN rows
      const int c = wid * BCW + cc;
      const int r = c * 16 + srow;
      gld_lds16(Bp + (size_t)r * K + ko + ((ssl ^ ((r >> 1) & 3)) * 8),
                &Bs[sbuf][c * 512]);
    }
  };

  // prologue: stage tiles 0,1,2; wait for tile 0 (own loads), barrier
  stage(0, 0);
  stage(1, 1);
  stage(2, 2);
  if (NREP == 4) { asm volatile("s_waitcnt vmcnt(8)" ::: "memory"); }
  else           { asm volatile("s_waitcnt vmcnt(6)" ::: "memory"); }
  __builtin_amdgcn_sched_barrier(0);
  __builtin_amdgcn_s_barrier();

  for (int kt = 0; kt < nk; ++kt) {
    const int cur = kt & 3;
    if (kt + 3 < nk) stage(kt + 3, (kt + 3) & 3);

    bf16x8 av[8], bv[NREP];
#pragma unroll
    for (int i = 0; i < 8; ++i) {
      const int r = wr * 128 + i * 16 + fr;
      av[i] = *(const bf16x8*)&As[cur][r * 32 + ((fq ^ ((r >> 1) & 3)) * 8)];
    }
#pragma unroll
    for (int j = 0; j < NREP; ++j) {
      const int r = wc * (NREP * 16) + j * 16 + fr;
      bv[j] = *(const bf16x8*)&Bs[cur][r * 32 + ((fq ^ ((r >> 1) & 3)) * 8)];
    }

    __builtin_amdgcn_s_setprio(1);
#pragma unroll
    for (int i = 0; i < 8; i++)
#pragma unroll
      for (int j = 0; j < NREP; j++)
        acc[i][j] = __builtin_amdgcn_mfma_f32_16x16x32_bf16(av[i], bv[j], acc[i][j], 0, 0, 0);
    __builtin_amdgcn_s_setprio(0);

    // leave the newest 2 tiles' loads in flight; tile kt+1 guaranteed landed
    if (kt + 3 < nk) {
      if (NREP == 4) { asm volatile("s_waitcnt vmcnt(8)" ::: "memory"); }
      else           { asm volatile("s_waitcnt vmcnt(6)" ::: "memory"); }
    } else if (kt + 3 == nk) {
      if (NREP == 4) { asm volatile("s_waitcnt vmcnt(4)" ::: "memory"); }
      else           { asm volatile("s_waitcnt vmcnt(3)" ::: "memory"); }
    } else {
      asm volatile("s_waitcnt vmcnt(0)" ::: "memory");
    }
    __builtin_amdgcn_sched_barrier(0);
    __builtin_amdgcn_s_barrier();
  }

  // epilogue
#pragma unroll
  for (int i = 0; i < 8; i++) {
#pragma unroll
    for (int j = 0; j < NREP; j++) {
      const int n = nloc + wc * (NREP * 16) + j * 16 + fr;
#pragma unroll
      for (int e = 0; e < 4; e++) {
        const int m = m0 + wr * 128 + i * 16 + fq * 4 + e;
        float val = acc[i][j][e];
        if (MODE == M_QKV) {
          const int b = m >> 10, s = m & 1023, h = n >> 7, d = n & 127;
          if (which == 0)      Cf[((size_t)(b * NH + h) * Ss + s) * HD + d] = val;
          else if (which == 1) Ck[((size_t)(b * NKV + h) * Ss + s) * HD + d] = val;
          else                 Cv[((size_t)(b * NKV + h) * HD + d) * Ss + s] = val;
        } else {  // M_OUT
          Cf[(size_t)m * HID + n] = val;
        }
      }
    }
  }
}

// ---------------------------------------------------------------------------
// Fused causal attention, block-cooperative (unchanged from R4/R5):
//   block = (a, bh): 64 q-rows, 4 waves x 16 rows, nt = a+1 k-tiles.
// ---------------------------------------------------------------------------
__global__ __launch_bounds__(256) void fused_attn(
    const u16* __restrict__ qb,   // [B*NH*S][128]
    const u16* __restrict__ kb,   // [B*NKV*S][128]
    const u16* __restrict__ vTb,  // [B*NKV][128][1024]
    float* __restrict__ wout,     // [B*NH][1024][1024]
    u16* __restrict__ attnb) {    // [B*S][4096]
  __shared__ u16 Ks[64 * 128];
  __shared__ u16 Vs[128 * 64];
  __shared__ u16 plds[4][16 * 64];
  __shared__ float scl_l[4][16];

  const int a = 15 - (int)(blockIdx.x >> 6);  // heavy blocks first
  const int bh = blockIdx.x & 63;
  const int b = bh >> 5, h = bh & 31;
  const int kv = h >> 2;
  const int tid = threadIdx.x;
  const int lane = tid & 63;
  const int wq = tid >> 6;
  const int fr = lane & 15, fq = lane >> 4;

  const int nt = a + 1;
  const int Q0 = a * 64;
  const int qw0 = Q0 + wq * 16;

  const u16* Kb = kb + (size_t)(b * NKV + kv) * Ss * HD;
  const u16* Vb = vTb + (size_t)(b * NKV + kv) * HD * Ss;
  float* wrow = wout + (size_t)bh * Ss * Ss;

  // zero-fill fully-masked columns [nt*64, 1024)
  if (a < 15) {
    const int base = 64 * nt;
    const int n4 = 16 * (15 - a);
#pragma unroll
    for (int r0 = 0; r0 < 4; ++r0) {
      const int row = Q0 + r0 * 16 + (tid >> 4);
      float4* wp = (float4*)&wrow[(size_t)row * Ss + base];
      for (int c = tid & 15; c < n4; c += 16) wp[c] = float4{0.f, 0.f, 0.f, 0.f};
    }
  }

  // Q fragments (reused by both sweeps)
  bf16x8 qf[4];
#pragma unroll
  for (int kk = 0; kk < 4; kk++)
    qf[kk] = *(const bf16x8*)&qb[((size_t)bh * Ss + qw0 + fr) * HD + kk * 32 + fq * 8];

  // ================= sweep 1: online m, l =================
  float m[4], l[4];
#pragma unroll
  for (int i = 0; i < 4; i++) { m[i] = -1e30f; l[i] = 0.f; }

  for (int t = 0; t < nt; ++t) {
    __syncthreads();
#pragma unroll
    for (int c = 0; c < 4; ++c) {
      const int idx0 = (c * 4 + wq) * 64;
      const int idx = idx0 + lane;
      const int row = idx >> 4, sl = idx & 15;
      const int slot = sl ^ (row & 15);
      gld_lds16(Kb + (size_t)(t * 64 + row) * HD + slot * 8, &Ks[idx0 * 8]);
    }
    __syncthreads();

    f32x4 sa[4];
#pragma unroll
    for (int jn = 0; jn < 4; jn++) sa[jn] = (f32x4){0.f, 0.f, 0.f, 0.f};
#pragma unroll
    for (int kk = 0; kk < 4; ++kk) {
      bf16x8 kfv[4];
#pragma unroll
      for (int jn = 0; jn < 4; ++jn) {
        const int row = jn * 16 + fr;
        kfv[jn] = *(const bf16x8*)&Ks[row * 128 + (((kk * 4 + fq) ^ fr) * 8)];
      }
#pragma unroll
      for (int jn = 0; jn < 4; ++jn)
        sa[jn] = __builtin_amdgcn_mfma_f32_16x16x32_bf16(qf[kk], kfv[jn], sa[jn], 0, 0, 0);
    }

    const bool diag = (t == a);
#pragma unroll
    for (int e = 0; e < 4; ++e) {
      const int qrow = qw0 + fq * 4 + e;
      float sv[4];
      float rmax = -1e30f;
#pragma unroll
      for (int jn = 0; jn < 4; ++jn) {
        float s = sa[jn][e] * SCALING;
        if (diag && (t * 64 + jn * 16 + fr > qrow)) s = -1e30f;
        sv[jn] = s;
        rmax = fmaxf(rmax, s);
      }
#pragma unroll
      for (int o = 1; o < 16; o <<= 1) rmax = fmaxf(rmax, __shfl_xor(rmax, o));
      const float mn = fmaxf(m[e], rmax);
      const float cc = __expf(m[e] - mn);
      float rs = __expf(sv[0] - mn) + __expf(sv[1] - mn) +
                 __expf(sv[2] - mn) + __expf(sv[3] - mn);
#pragma unroll
      for (int o = 1; o < 16; o <<= 1) rs += __shfl_xor(rs, o);
      l[e] = l[e] * cc + rs;
      m[e] = mn;
    }
  }

  float scl[4];
#pragma unroll
  for (int e = 0; e < 4; e++) scl[e] = 1.f / (255.f * l[e]);
  if (fr == 0) {
#pragma unroll
    for (int e = 0; e < 4; e++) scl_l[wq][fq * 4 + e] = scl[e];
  }

  // ================= sweep 2: emit w + PV =================
  f32x4 acc2[8];
#pragma unroll
  for (int j = 0; j < 8; j++) acc2[j] = (f32x4){0.f, 0.f, 0.f, 0.f};

  u16* pl = &plds[wq][0];
  const int wrrow = lane >> 2, wrq = lane & 3;
  const float sclr = scl_l[wq][wrrow];

  for (int t = 0; t < nt; ++t) {
    __syncthreads();
#pragma unroll
    for (int c = 0; c < 4; ++c) {
      const int idx0 = (c * 4 + wq) * 64;
      const int idx = idx0 + lane;
      {
        const int row = idx >> 4, sl = idx & 15;
        const int slot = sl ^ (row & 15);
        gld_lds16(Kb + (size_t)(t * 64 + row) * HD + slot * 8, &Ks[idx0 * 8]);
      }
      {
        const int d = idx >> 3, sl = idx & 7;
        const int slot = sl ^ (d & 7);
        gld_lds16(Vb + (size_t)d * Ss + t * 64 + slot * 8, &Vs[idx0 * 8]);
      }
    }
    __syncthreads();

    f32x4 sa[4];
#pragma unroll
    for (int jn = 0; jn < 4; jn++) sa[jn] = (f32x4){0.f, 0.f, 0.f, 0.f};
#pragma unroll
    for (int kk = 0; kk < 4; ++kk) {
      bf16x8 kfv[4];
#pragma unroll
      for (int jn = 0; jn < 4; ++jn) {
        const int row = jn * 16 + fr;
        kfv[jn] = *(const bf16x8*)&Ks[row * 128 + (((kk * 4 + fq) ^ fr) * 8)];
      }
#pragma unroll
      for (int jn = 0; jn < 4; ++jn)
        sa[jn] = __builtin_amdgcn_mfma_f32_16x16x32_bf16(qf[kk], kfv[jn], sa[jn], 0, 0, 0);
    }

    const bool diag = (t == a);
#pragma unroll
    for (int e = 0; e < 4; ++e) {
      const int qrow = qw0 + fq * 4 + e;
      const int r16 = fq * 4 + e;
#pragma unroll
      for (int jn = 0; jn < 4; ++jn) {
        const int kc = t * 64 + jn * 16 + fr;
        float qv = 0.f;
        if (!diag || kc <= qrow)
          qv = rintf(fminf(255.f * __expf(sa[jn][e] * SCALING - m[e]), 255.f));
        const int col = jn * 16 + fr;
        const int byte = r16 * 128 + (((col >> 3) ^ (r16 & 7)) * 16) + (col & 7) * 2;
        *(u16*)((char*)pl + byte) = f2bf(qv);
      }
    }

    // vectorized w write
    {
      const int s0 = (2 * wrq) ^ (wrrow & 7);
      const int s1 = (2 * wrq + 1) ^ (wrrow & 7);
      bf16x8 p0 = *(const bf16x8*)((char*)pl + wrrow * 128 + s0 * 16);
      bf16x8 p1 = *(const bf16x8*)((char*)pl + wrrow * 128 + s1 * 16);
      float* wp = &wrow[(size_t)(qw0 + wrrow) * Ss + t * 64 + wrq * 16];
      float4 o0, o1, o2, o3;
      o0.x = (float)p0[0] * sclr; o0.y = (float)p0[1] * sclr;
      o0.z = (float)p0[2] * sclr; o0.w = (float)p0[3] * sclr;
      o1.x = (float)p0[4] * sclr; o1.y = (float)p0[5] * sclr;
      o1.z = (float)p0[6] * sclr; o1.w = (float)p0[7] * sclr;
      o2.x = (float)p1[0] * sclr; o2.y = (float)p1[1] * sclr;
      o2.z = (float)p1[2] * sclr; o2.w = (float)p1[3] * sclr;
      o3.x = (float)p1[4] * sclr; o3.y = (float)p1[5] * sclr;
      o3.z = (float)p1[6] * sclr; o3.w = (float)p1[7] * sclr;
      ((float4*)wp)[0] = o0; ((float4*)wp)[1] = o1;
      ((float4*)wp)[2] = o2; ((float4*)wp)[3] = o3;
    }

    // PV
#pragma unroll
    for (int kk2 = 0; kk2 < 2; ++kk2) {
      const bf16x8 pa = *(const bf16x8*)((char*)pl + fr * 128 + (((kk2 * 4 + fq) ^ (fr & 7)) * 16));
#pragma unroll
      for (int jn2 = 0; jn2 < 8; ++jn2) {
        const int d = jn2 * 16 + fr;
        const bf16x8 vb = *(const bf16x8*)&Vs[d * 64 + (((kk2 * 4 + fq) ^ (d & 7)) * 8)];
        acc2[jn2] = __builtin_amdgcn_mfma_f32_16x16x32_bf16(pa, vb, acc2[jn2], 0, 0, 0);
      }
    }
  }

  // epilogue: attn -> bf16 [B*S][NH*HD]
#pragma unroll
  for (int e = 0; e < 4; ++e) {
    const int qrow = qw0 + fq * 4 + e;
#pragma unroll
    for (int jn2 = 0; jn2 < 8; ++jn2)
      attnb[((size_t)b * Ss + qrow) * HID + h * HD + jn2 * 16 + fr] =
          f2bf(acc2[jn2][e] * scl[e]);
  }
}

// ---------------------------------------------------------------------------
// One-shot fp32 -> bf16 conversion of hs + all 4 weights (segmented grid).
// Segment sizes in 2048-element blocks (compile-time constants).
constexpr int CB_HS = Bb * Ss * HID / 2048;       // 4096
constexpr int CB_WQ = NH * HD * HID / 2048;       // 8192
constexpr int CB_WK = NKV * HD * HID / 2048;      // 2048
constexpr int CB_WV = CB_WK;                      // 2048
constexpr int CB_WO = HID * NH * HD / 2048;       // 8192

__global__ __launch_bounds__(256) void convert_all(
    const float* __restrict__ hs, const float* __restrict__ wq,
    const float* __restrict__ wk, const float* __restrict__ wv,
    const float* __restrict__ wo,
    u16* __restrict__ hsb, u16* __restrict__ wqb, u16* __restrict__ wkb,
    u16* __restrict__ wvb, u16* __restrict__ wob) {
  const int bid = blockIdx.x;
  const float* src;
  u16* dst;
  int base;
  if (bid < CB_HS) { src = hs; dst = hsb; base = 0; }
  else if (bid < CB_HS + CB_WQ) { src = wq; dst = wqb; base = CB_HS; }
  else if (bid < CB_HS + CB_WQ + CB_WK) { src = wk; dst = wkb; base = CB_HS + CB_WQ; }
  else if (bid < CB_HS + CB_WQ + CB_WK + CB_WV) { src = wv; dst = wvb; base = CB_HS + CB_WQ + CB_WK; }
  else { src = wo; dst = wob; base = CB_HS + CB_WQ + CB_WK + CB_WV; }
  const int i = (bid - base) * 256 + threadIdx.x;
  float4 a = ((const float4*)src)[2 * i];
  float4 b = ((const float4*)src)[2 * i + 1];
  u16x8 t;
  t[0] = f2bf(a.x); t[1] = f2bf(a.y); t[2] = f2bf(a.z); t[3] = f2bf(a.w);
  t[4] = f2bf(b.x); t[5] = f2bf(b.y); t[6] = f2bf(b.z); t[7] = f2bf(b.w);
  ((u16x8*)dst)[i] = t;
}

// RoPE + per-row asymmetric 8-bit fake-quant for q -> bf16. One wave per row.
__global__ __launch_bounds__(256) void rope_quant_q(const float* __restrict__ q,
                                                    u16* __restrict__ qb,
                                                    const float* __restrict__ cs,
                                                    const float* __restrict__ sn) {
  const int row = blockIdx.x * 4 + (threadIdx.x >> 6);
  const int lane = threadIdx.x & 63;
  const int s = row & (Ss - 1);
  const int b = row >> 15;
  const float* p = q + (size_t)row * HD;
  const float* cp = cs + ((size_t)b * Ss + s) * HD;
  const float* sp = sn + ((size_t)b * Ss + s) * HD;
  float x1 = p[lane], x2 = p[lane + 64];
  float r1 = x1 * cp[lane] - x2 * sp[lane];
  float r2 = x2 * cp[lane + 64] + x1 * sp[lane + 64];
  float mn = fminf(0.f, fminf(r1, r2));
  float mx = fmaxf(0.f, fmaxf(r1, r2));
#pragma unroll
  for (int o = 32; o; o >>= 1) {
    mn = fminf(mn, __shfl_xor(mn, o));
    mx = fmaxf(mx, __shfl_xor(mx, o));
  }
  float rng = mx - mn;
  float scale = (rng == 0.f) ? 1.f : rng / 255.f;
  float zero = rintf(-mn / scale);
  float q1 = fminf(fmaxf(rintf(r1 / scale) + zero, 0.f), 255.f);
  float q2 = fminf(fmaxf(rintf(r2 / scale) + zero, 0.f), 255.f);
  qb[(size_t)row * HD + lane] = f2bf((q1 - zero) * scale);
  qb[(size_t)row * HD + lane + 64] = f2bf((q2 - zero) * scale);
}

// RoPE only for k. One wave per row, in place.
__global__ __launch_bounds__(256) void rope_k(float* __restrict__ k,
                                              const float* __restrict__ cs,
                                              const float* __restrict__ sn) {
  const int row = blockIdx.x * 4 + (threadIdx.x >> 6);
  const int lane = threadIdx.x & 63;
  const int s = row & (Ss - 1);
  const int b = row >> 13;
  float* p = k + (size_t)row * HD;
  const float* cp = cs + ((size_t)b * Ss + s) * HD;
  const float* sp = sn + ((size_t)b * Ss + s) * HD;
  float x1 = p[lane], x2 = p[lane + 64];
  float r1 = x1 * cp[lane] - x2 * sp[lane];
  float r2 = x2 * cp[lane + 64] + x1 * sp[lane + 64];
  p[lane] = r1;
  p[lane + 64] = r2;
}

// Mean of k over S per (b,h,d). One 1024-thread block per (b,h).
__global__ __launch_bounds__(1024) void kmean_kernel(const float* __restrict__ k,
                                                     float* __restrict__ kmean) {
  const int bh = blockIdx.x;
  const int d = threadIdx.x & 127;
  const int sl = threadIdx.x >> 7;
  const float* p = k + (size_t)bh * Ss * HD;
  float sum = 0.f;
  for (int s = sl; s < Ss; s += 8) sum += p[(size_t)s * HD + d];
  __shared__ float lds[8][128];
  lds[sl][d] = sum;
  __syncthreads();
  if (threadIdx.x < 128) {
    float t = 0.f;
#pragma unroll
    for (int i = 0; i < 8; i++) t += lds[i][threadIdx.x];
    kmean[bh * HD + threadIdx.x] = t * (1.f / 1024.f);
  }
}

// Subtract mean + per-row quant for k -> bf16. One wave per row.
__global__ __launch_bounds__(256) void k_subquant(const float* __restrict__ k,
                                                  u16* __restrict__ kb,
                                                  const float* __restrict__ kmean) {
  const int row = blockIdx.x * 4 + (threadIdx.x >> 6);
  const int lane = threadIdx.x & 63;
  const int bh = row >> 10;
  const float* p = k + (size_t)row * HD;
  float x1 = p[lane] - kmean[bh * HD + lane];
  float x2 = p[lane + 64] - kmean[bh * HD + lane + 64];
  float mn = fminf(0.f, fminf(x1, x2));
  float mx = fmaxf(0.f, fmaxf(x1, x2));
#pragma unroll
  for (int o = 32; o; o >>= 1) {
    mn = fminf(mn, __shfl_xor(mn, o));
    mx = fmaxf(mx, __shfl_xor(mx, o));
  }
  float rng = mx - mn;
  float scale = (rng == 0.f) ? 1.f : rng / 255.f;
  float zero = rintf(-mn / scale);
  float q1 = fminf(fmaxf(rintf(x1 / scale) + zero, 0.f), 255.f);
  float q2 = fminf(fmaxf(rintf(x2 / scale) + zero, 0.f), 255.f);
  kb[(size_t)row * HD + lane] = f2bf((q1 - zero) * scale);
  kb[(size_t)row * HD + lane + 64] = f2bf((q2 - zero) * scale);
}

// Per-(b,h,d) quant of v over S (vT rows) -> bf16. One block per row.
__global__ __launch_bounds__(256) void vquant(const float* __restrict__ vT,
                                              u16* __restrict__ vTb) {
  const float* p = vT + (size_t)blockIdx.x * Ss;
  const int t = threadIdx.x;
  float4 x = ((const float4*)p)[t];
  float mn = fminf(0.f, fminf(fminf(x.x, x.y), fminf(x.z, x.w)));
  float mx = fmaxf(0.f, fmaxf(fmaxf(x.x, x.y), fmaxf(x.z, x.w)));
#pragma unroll
  for (int o = 32; o; o >>= 1) {
    mn = fminf(mn, __shfl_xor(mn, o));
    mx = fmaxf(mx, __shfl_xor(mx, o));
  }
  __shared__ float smn[4], smx[4];
  const int wid = t >> 6, lane = t & 63;
  if (lane == 0) { smn[wid] = mn; smx[wid] = mx; }
  __syncthreads();
  mn = fminf(fminf(smn[0], smn[1]), fminf(smn[2], smn[3]));
  mx = fmaxf(fmaxf(smx[0], smx[1]), fmaxf(smx[2], smx[3]));
  float rng = mx - mn;
  float scale = (rng == 0.f) ? 1.f : rng / 255.f;
  float zero = rintf(-mn / scale);
  u16x4 o4;
  o4[0] = f2bf((fminf(fmaxf(rintf(x.x / scale) + zero, 0.f), 255.f) - zero) * scale);
  o4[1] = f2bf((fminf(fmaxf(rintf(x.y / scale) + zero, 0.f), 255.f) - zero) * scale);
  o4[2] = f2bf((fminf(fmaxf(rintf(x.z / scale) + zero, 0.f), 255.f) - zero) * scale);
  o4[3] = f2bf((fminf(fmaxf(rintf(x.w / scale) + zero, 0.f), 255.f) - zero) * scale);
  ((u16x4*)vTb)[(size_t)blockIdx.x * 256 + t] = o4;
}

// ---------------------------------------------------------------------------
extern "C" void kernel_launch(void* const* d_in, const int* in_sizes, int n_in,
                              void* d_out, int out_size, void* d_ws, size_t ws_size,
                              hipStream_t stream) {
  const float* hs = (const float*)d_in[0];
  const float* cosp = (const float*)d_in[1];
  const float* sinp = (const float*)d_in[2];
  const float* Wq = (const float*)d_in[4];
  const float* Wk = (const float*)d_in[5];
  const float* Wv = (const float*)d_in[6];
  const float* Wo = (const float*)d_in[7];

  float* out = (float*)d_out;
  float* wout = out + (size_t)Bb * Ss * HID;  // w output region (fp32)

  char* wsp = (char*)d_ws;
  auto alloc = [&](size_t bytes) {
    char* p = wsp;
    wsp += (bytes + 255) & ~(size_t)255;
    return p;
  };
  float* q     = (float*)alloc((size_t)Bb * NH * Ss * HD * 4);   // 33.6 MB
  float* k     = (float*)alloc((size_t)Bb * NKV * Ss * HD * 4);  // 8.4 MB
  float* vT    = (float*)alloc((size_t)Bb * NKV * Ss * HD * 4);  // 8.4 MB
  float* kmean = (float*)alloc((size_t)Bb * NKV * HD * 4);
  u16* hsb = (u16*)alloc((size_t)Bb * Ss * HID * 2);
  u16* qb  = (u16*)alloc((size_t)Bb * NH * Ss * HD * 2);
  u16* kb  = (u16*)alloc((size_t)Bb * NKV * Ss * HD * 2);
  u16* vTb = (u16*)alloc((size_t)Bb * NKV * Ss * HD * 2);
  u16* Wqb = (u16*)alloc((size_t)NH * HD * HID * 2);
  u16* Wkb = (u16*)alloc((size_t)NKV * HD * HID * 2);
  u16* Wvb = (u16*)alloc((size_t)NKV * HD * HID * 2);
  u16* Wob = (u16*)alloc((size_t)HID * NH * HD * 2);
  u16* attnb = (u16*)q;  // q fp32 dead after rope_quant_q; reuse

  // fp32 -> bf16 conversions (single dispatch)
  convert_all<<<CB_HS + CB_WQ + CB_WK + CB_WV + CB_WO, 256, 0, stream>>>(
      hs, Wq, Wk, Wv, Wo, hsb, Wqb, Wkb, Wvb, Wob);

  // fused Q/K/V projection (256x256 tiles, 24 x 8 = 192 blocks)
  mfma_gemm<M_QKV, 4><<<dim3(24, 8), 512, 0, stream>>>(
      hsb, Wqb, Wkb, Wvb, q, k, vT, HID);

  // RoPE / mean-center / quantize
  rope_quant_q<<<(Bb * NH * Ss) / 4, 256, 0, stream>>>(q, qb, cosp, sinp);
  rope_k<<<(Bb * NKV * Ss) / 4, 256, 0, stream>>>(k, cosp, sinp);
  kmean_kernel<<<Bb * NKV, 1024, 0, stream>>>(k, kmean);
  k_subquant<<<(Bb * NKV * Ss) / 4, 256, 0, stream>>>(k, kb, kmean);
  vquant<<<Bb * NKV * HD, 256, 0, stream>>>(vT, vTb);

  // fused scores+softmax+quant(w)+PV  (1024 uniform-work blocks, heavy first)
  fused_attn<<<dim3(1024), 256, 0, stream>>>(qb, kb, vTb, wout, attnb);

  // out = attn @ Wo^T (256x128 tiles, 32 x 8 = 256 blocks = 1/CU)
  mfma_gemm<M_OUT, 2><<<dim3(32, 8), 512, 0, stream>>>(
      attnb, Wob, nullptr, nullptr, out, nullptr, nullptr, HID);
}

// Round 7
// 442.040 us; speedup vs baseline: 1.5471x; 1.0102x over previous
//
#include <hip/hip_runtime.h>
#include <math.h>
#include <stdint.h>

typedef unsigned int u32;
typedef unsigned short u16;
typedef __bf16 bf16x8 __attribute__((ext_vector_type(8)));
typedef float f32x4 __attribute__((ext_vector_type(4)));
typedef unsigned short u16x8 __attribute__((ext_vector_type(8)));
typedef unsigned short u16x4 __attribute__((ext_vector_type(4)));

constexpr int   Bb  = 2;
constexpr int   Ss  = 1024;
constexpr int   HID = 4096;
constexpr int   NH  = 32;
constexpr int   NKV = 8;
constexpr int   HD  = 128;
constexpr float SCALING = 0.0883883476483184405501f; // 128^-0.5

enum { M_QKV = 0, M_OUT = 3 };

// fp32 -> bf16 RTNE (bit trick; finite values only here)
__device__ __forceinline__ u16 f2bf(float f) {
  u32 u = __builtin_bit_cast(u32, f);
  u = u + 0x7fffu + ((u >> 16) & 1u);
  return (u16)(u >> 16);
}

// async global->LDS, 16B per lane; LDS dest = wave-uniform base (+ lane*16 by HW)
__device__ __forceinline__ void gld_lds16(const void* g, void* l) {
  __builtin_amdgcn_global_load_lds(
      (const __attribute__((address_space(1))) u32*)(uintptr_t)g,
      (__attribute__((address_space(3))) u32*)(uintptr_t)l, 16, 0, 0);
}

// ---------------------------------------------------------------------------
// bf16 MFMA GEMM, phase-templated (m201-style):
//   BM=128, BN=256, BK=64, 512 threads = 8 waves (2M x 4N), wave tile 64x64.
//   3 LDS buffers (144 KB) -> stage distance 2 K-tiles, steady vmcnt(6).
//   Per K-tile: 2 phases (ks=0/1): {8 ds_read_b128 | stage-issue -> barrier ->
//   lgkmcnt(0) -> setprio(1) -> 16 MFMA -> setprio(0)}.
//   Staging affinity: wave (wr,wc) stages exactly the A-half (rows wr*64..+64)
//   and B-quarter (rows wc*64..+64) it consumes -> per-wave vmcnt + barrier
//   guarantees residency. 16B-slot XOR swizzle (slot ^ (row&7)), pre-swizzled
//   global sources (linear LDS dest). K order identical to prior rounds.
// ---------------------------------------------------------------------------
template <int MODE>
__global__ __launch_bounds__(512) void mfma_gemm(
    const u16* __restrict__ Abf_g,
    const u16* __restrict__ B0, const u16* __restrict__ B1,
    const u16* __restrict__ B2,
    float* __restrict__ Cf, float* __restrict__ Ck, float* __restrict__ Cv,
    int K) {
  __shared__ u16 As[3][128 * 64];  // 3 x 16 KB
  __shared__ u16 Bs[3][256 * 64];  // 3 x 32 KB

  const int tid = threadIdx.x;
  const int lane = tid & 63;
  const int wid = tid >> 6;        // 0..7
  const int wr = wid >> 2;         // 0..1
  const int wc = wid & 3;          // 0..3
  const int fr = lane & 15;
  const int fq = lane >> 4;

  const int m0 = blockIdx.y * 128;
  int nloc = 0;

  const u16* Abf = Abf_g + (size_t)m0 * K;
  const u16* Bp = nullptr;
  int which = 0;

  if (MODE == M_QKV) {
    const int j = blockIdx.x;  // 0..23: 16 Q col-blocks, 4 K, 4 V (256 wide)
    if (j < 16)      { which = 0; Bp = B0 + (size_t)j * 256 * K;        nloc = j * 256; }
    else if (j < 20) { which = 1; Bp = B1 + (size_t)(j - 16) * 256 * K; nloc = (j - 16) * 256; }
    else             { which = 2; Bp = B2 + (size_t)(j - 20) * 256 * K; nloc = (j - 20) * 256; }
  } else {  // M_OUT
    Bp = B0 + (size_t)blockIdx.x * 256 * K;
    nloc = blockIdx.x * 256;
  }

  f32x4 acc[4][4];
#pragma unroll
  for (int i = 0; i < 4; i++)
#pragma unroll
    for (int j = 0; j < 4; j++) acc[i][j] = (f32x4){0.f, 0.f, 0.f, 0.f};

  const int arow0 = wr * 64 + wc * 16;  // A stage base (2 gld x 8 rows)
  const int brow0 = wc * 64 + wr * 32;  // B stage base (4 gld x 8 rows)
  const int sub8 = lane >> 3;           // row-in-8 for staging
  const int sl8 = lane & 7;             // 16B slot (pre-swizzle)

  auto stageA = [&](int t, int s) {
    const int ko = t * 64;
#pragma unroll
    for (int g = 0; g < 2; ++g) {
      const int r0 = arow0 + g * 8;
      const int row = r0 + sub8;
      gld_lds16(Abf + (size_t)row * K + ko + ((sl8 ^ (row & 7)) * 8),
                &As[s][r0 * 64]);
    }
  };
  auto stageB2 = [&](int t, int s, int gbase) {
    const int ko = t * 64;
#pragma unroll
    for (int g = 0; g < 2; ++g) {
      const int r0 = brow0 + (gbase + g) * 8;
      const int row = r0 + sub8;
      gld_lds16(Bp + (size_t)row * K + ko + ((sl8 ^ (row & 7)) * 8),
                &Bs[s][r0 * 64]);
    }
  };

  const int nk = K >> 6;  // K-tiles of 64

  // prologue: stage tiles 0 and 1 (6 loads each per wave)
  stageA(0, 0); stageB2(0, 0, 0); stageB2(0, 0, 2);
  stageA(1, 1); stageB2(1, 1, 0); stageB2(1, 1, 2);
  asm volatile("s_waitcnt vmcnt(6)" ::: "memory");  // tile 0 landed
  __builtin_amdgcn_sched_barrier(0);
  __builtin_amdgcn_s_barrier();

  int buf = 0, nxt = 2;
  for (int kt = 0; kt < nk; ++kt) {
    const bool st = (kt + 2 < nk);

    // -------- phase 0: ks = 0 --------
    {
      bf16x8 av[4], bv[4];
#pragma unroll
      for (int i = 0; i < 4; ++i) {
        const int r = wr * 64 + i * 16 + fr;
        av[i] = *(const bf16x8*)&As[buf][r * 64 + ((fq ^ (r & 7)) * 8)];
      }
#pragma unroll
      for (int j = 0; j < 4; ++j) {
        const int r = wc * 64 + j * 16 + fr;
        bv[j] = *(const bf16x8*)&Bs[buf][r * 64 + ((fq ^ (r & 7)) * 8)];
      }
      if (st) { stageA(kt + 2, nxt); stageB2(kt + 2, nxt, 0); }
      __builtin_amdgcn_s_barrier();
      asm volatile("s_waitcnt lgkmcnt(0)" ::: "memory");
      __builtin_amdgcn_sched_barrier(0);
      __builtin_amdgcn_s_setprio(1);
#pragma unroll
      for (int i = 0; i < 4; i++)
#pragma unroll
        for (int j = 0; j < 4; j++)
          acc[i][j] = __builtin_amdgcn_mfma_f32_16x16x32_bf16(av[i], bv[j], acc[i][j], 0, 0, 0);
      __builtin_amdgcn_s_setprio(0);
    }

    // -------- phase 1: ks = 1 --------
    {
      bf16x8 av[4], bv[4];
#pragma unroll
      for (int i = 0; i < 4; ++i) {
        const int r = wr * 64 + i * 16 + fr;
        av[i] = *(const bf16x8*)&As[buf][r * 64 + (((4 + fq) ^ (r & 7)) * 8)];
      }
#pragma unroll
      for (int j = 0; j < 4; ++j) {
        const int r = wc * 64 + j * 16 + fr;
        bv[j] = *(const bf16x8*)&Bs[buf][r * 64 + (((4 + fq) ^ (r & 7)) * 8)];
      }
      if (st) { stageB2(kt + 2, nxt, 2); }
      __builtin_amdgcn_s_barrier();
      asm volatile("s_waitcnt lgkmcnt(0)" ::: "memory");
      __builtin_amdgcn_sched_barrier(0);
      __builtin_amdgcn_s_setprio(1);
#pragma unroll
      for (int i = 0; i < 4; i++)
#pragma unroll
        for (int j = 0; j < 4; j++)
          acc[i][j] = __builtin_amdgcn_mfma_f32_16x16x32_bf16(av[i], bv[j], acc[i][j], 0, 0, 0);
      __builtin_amdgcn_s_setprio(0);
    }

    // -------- tile end: counted vmcnt (never 0 mid-loop) --------
    if (st) {
      asm volatile("s_waitcnt vmcnt(6)" ::: "memory");  // tile kt+1 landed
    } else {
      asm volatile("s_waitcnt vmcnt(0)" ::: "memory");
    }
    __builtin_amdgcn_sched_barrier(0);
    __builtin_amdgcn_s_barrier();
    buf = (buf == 2) ? 0 : buf + 1;
    nxt = (nxt == 2) ? 0 : nxt + 1;
  }

  // epilogue
#pragma unroll
  for (int i = 0; i < 4; i++) {
#pragma unroll
    for (int j = 0; j < 4; j++) {
      const int n = nloc + wc * 64 + j * 16 + fr;
#pragma unroll
      for (int e = 0; e < 4; e++) {
        const int m = m0 + wr * 64 + i * 16 + fq * 4 + e;
        float val = acc[i][j][e];
        if (MODE == M_QKV) {
          const int b = m >> 10, s = m & 1023, h = n >> 7, d = n & 127;
          if (which == 0)      Cf[((size_t)(b * NH + h) * Ss + s) * HD + d] = val;
          else if (which == 1) Ck[((size_t)(b * NKV + h) * Ss + s) * HD + d] = val;
          else                 Cv[((size_t)(b * NKV + h) * HD + d) * Ss + s] = val;
        } else {  // M_OUT
          Cf[(size_t)m * HID + n] = val;
        }
      }
    }
  }
}

// ---------------------------------------------------------------------------
// Fused causal attention, block-cooperative (unchanged):
//   block = (a, bh): 64 q-rows, 4 waves x 16 rows, nt = a+1 k-tiles.
// ---------------------------------------------------------------------------
__global__ __launch_bounds__(256) void fused_attn(
    const u16* __restrict__ qb,   // [B*NH*S][128]
    const u16* __restrict__ kb,   // [B*NKV*S][128]
    const u16* __restrict__ vTb,  // [B*NKV][128][1024]
    float* __restrict__ wout,     // [B*NH][1024][1024]
    u16* __restrict__ attnb) {    // [B*S][4096]
  __shared__ u16 Ks[64 * 128];
  __shared__ u16 Vs[128 * 64];
  __shared__ u16 plds[4][16 * 64];
  __shared__ float scl_l[4][16];

  const int a = 15 - (int)(blockIdx.x >> 6);  // heavy blocks first
  const int bh = blockIdx.x & 63;
  const int b = bh >> 5, h = bh & 31;
  const int kv = h >> 2;
  const int tid = threadIdx.x;
  const int lane = tid & 63;
  const int wq = tid >> 6;
  const int fr = lane & 15, fq = lane >> 4;

  const int nt = a + 1;
  const int Q0 = a * 64;
  const int qw0 = Q0 + wq * 16;

  const u16* Kb = kb + (size_t)(b * NKV + kv) * Ss * HD;
  const u16* Vb = vTb + (size_t)(b * NKV + kv) * HD * Ss;
  float* wrow = wout + (size_t)bh * Ss * Ss;

  // zero-fill fully-masked columns [nt*64, 1024)
  if (a < 15) {
    const int base = 64 * nt;
    const int n4 = 16 * (15 - a);
#pragma unroll
    for (int r0 = 0; r0 < 4; ++r0) {
      const int row = Q0 + r0 * 16 + (tid >> 4);
      float4* wp = (float4*)&wrow[(size_t)row * Ss + base];
      for (int c = tid & 15; c < n4; c += 16) wp[c] = float4{0.f, 0.f, 0.f, 0.f};
    }
  }

  // Q fragments (reused by both sweeps)
  bf16x8 qf[4];
#pragma unroll
  for (int kk = 0; kk < 4; kk++)
    qf[kk] = *(const bf16x8*)&qb[((size_t)bh * Ss + qw0 + fr) * HD + kk * 32 + fq * 8];

  // ================= sweep 1: online m, l =================
  float m[4], l[4];
#pragma unroll
  for (int i = 0; i < 4; i++) { m[i] = -1e30f; l[i] = 0.f; }

  for (int t = 0; t < nt; ++t) {
    __syncthreads();
#pragma unroll
    for (int c = 0; c < 4; ++c) {
      const int idx0 = (c * 4 + wq) * 64;
      const int idx = idx0 + lane;
      const int row = idx >> 4, sl = idx & 15;
      const int slot = sl ^ (row & 15);
      gld_lds16(Kb + (size_t)(t * 64 + row) * HD + slot * 8, &Ks[idx0 * 8]);
    }
    __syncthreads();

    f32x4 sa[4];
#pragma unroll
    for (int jn = 0; jn < 4; jn++) sa[jn] = (f32x4){0.f, 0.f, 0.f, 0.f};
#pragma unroll
    for (int kk = 0; kk < 4; ++kk) {
      bf16x8 kfv[4];
#pragma unroll
      for (int jn = 0; jn < 4; ++jn) {
        const int row = jn * 16 + fr;
        kfv[jn] = *(const bf16x8*)&Ks[row * 128 + (((kk * 4 + fq) ^ fr) * 8)];
      }
#pragma unroll
      for (int jn = 0; jn < 4; ++jn)
        sa[jn] = __builtin_amdgcn_mfma_f32_16x16x32_bf16(qf[kk], kfv[jn], sa[jn], 0, 0, 0);
    }

    const bool diag = (t == a);
#pragma unroll
    for (int e = 0; e < 4; ++e) {
      const int qrow = qw0 + fq * 4 + e;
      float sv[4];
      float rmax = -1e30f;
#pragma unroll
      for (int jn = 0; jn < 4; ++jn) {
        float s = sa[jn][e] * SCALING;
        if (diag && (t * 64 + jn * 16 + fr > qrow)) s = -1e30f;
        sv[jn] = s;
        rmax = fmaxf(rmax, s);
      }
#pragma unroll
      for (int o = 1; o < 16; o <<= 1) rmax = fmaxf(rmax, __shfl_xor(rmax, o));
      const float mn = fmaxf(m[e], rmax);
      const float cc = __expf(m[e] - mn);
      float rs = __expf(sv[0] - mn) + __expf(sv[1] - mn) +
                 __expf(sv[2] - mn) + __expf(sv[3] - mn);
#pragma unroll
      for (int o = 1; o < 16; o <<= 1) rs += __shfl_xor(rs, o);
      l[e] = l[e] * cc + rs;
      m[e] = mn;
    }
  }

  float scl[4];
#pragma unroll
  for (int e = 0; e < 4; e++) scl[e] = 1.f / (255.f * l[e]);
  if (fr == 0) {
#pragma unroll
    for (int e = 0; e < 4; e++) scl_l[wq][fq * 4 + e] = scl[e];
  }

  // ================= sweep 2: emit w + PV =================
  f32x4 acc2[8];
#pragma unroll
  for (int j = 0; j < 8; j++) acc2[j] = (f32x4){0.f, 0.f, 0.f, 0.f};

  u16* pl = &plds[wq][0];
  const int wrrow = lane >> 2, wrq = lane & 3;
  const float sclr = scl_l[wq][wrrow];

  for (int t = 0; t < nt; ++t) {
    __syncthreads();
#pragma unroll
    for (int c = 0; c < 4; ++c) {
      const int idx0 = (c * 4 + wq) * 64;
      const int idx = idx0 + lane;
      {
        const int row = idx >> 4, sl = idx & 15;
        const int slot = sl ^ (row & 15);
        gld_lds16(Kb + (size_t)(t * 64 + row) * HD + slot * 8, &Ks[idx0 * 8]);
      }
      {
        const int d = idx >> 3, sl = idx & 7;
        const int slot = sl ^ (d & 7);
        gld_lds16(Vb + (size_t)d * Ss + t * 64 + slot * 8, &Vs[idx0 * 8]);
      }
    }
    __syncthreads();

    f32x4 sa[4];
#pragma unroll
    for (int jn = 0; jn < 4; jn++) sa[jn] = (f32x4){0.f, 0.f, 0.f, 0.f};
#pragma unroll
    for (int kk = 0; kk < 4; ++kk) {
      bf16x8 kfv[4];
#pragma unroll
      for (int jn = 0; jn < 4; ++jn) {
        const int row = jn * 16 + fr;
        kfv[jn] = *(const bf16x8*)&Ks[row * 128 + (((kk * 4 + fq) ^ fr) * 8)];
      }
#pragma unroll
      for (int jn = 0; jn < 4; ++jn)
        sa[jn] = __builtin_amdgcn_mfma_f32_16x16x32_bf16(qf[kk], kfv[jn], sa[jn], 0, 0, 0);
    }

    const bool diag = (t == a);
#pragma unroll
    for (int e = 0; e < 4; ++e) {
      const int qrow = qw0 + fq * 4 + e;
      const int r16 = fq * 4 + e;
#pragma unroll
      for (int jn = 0; jn < 4; ++jn) {
        const int kc = t * 64 + jn * 16 + fr;
        float qv = 0.f;
        if (!diag || kc <= qrow)
          qv = rintf(fminf(255.f * __expf(sa[jn][e] * SCALING - m[e]), 255.f));
        const int col = jn * 16 + fr;
        const int byte = r16 * 128 + (((col >> 3) ^ (r16 & 7)) * 16) + (col & 7) * 2;
        *(u16*)((char*)pl + byte) = f2bf(qv);
      }
    }

    // vectorized w write
    {
      const int s0 = (2 * wrq) ^ (wrrow & 7);
      const int s1 = (2 * wrq + 1) ^ (wrrow & 7);
      bf16x8 p0 = *(const bf16x8*)((char*)pl + wrrow * 128 + s0 * 16);
      bf16x8 p1 = *(const bf16x8*)((char*)pl + wrrow * 128 + s1 * 16);
      float* wp = &wrow[(size_t)(qw0 + wrrow) * Ss + t * 64 + wrq * 16];
      float4 o0, o1, o2, o3;
      o0.x = (float)p0[0] * sclr; o0.y = (float)p0[1] * sclr;
      o0.z = (float)p0[2] * sclr; o0.w = (float)p0[3] * sclr;
      o1.x = (float)p0[4] * sclr; o1.y = (float)p0[5] * sclr;
      o1.z = (float)p0[6] * sclr; o1.w = (float)p0[7] * sclr;
      o2.x = (float)p1[0] * sclr; o2.y = (float)p1[1] * sclr;
      o2.z = (float)p1[2] * sclr; o2.w = (float)p1[3] * sclr;
      o3.x = (float)p1[4] * sclr; o3.y = (float)p1[5] * sclr;
      o3.z = (float)p1[6] * sclr; o3.w = (float)p1[7] * sclr;
      ((float4*)wp)[0] = o0; ((float4*)wp)[1] = o1;
      ((float4*)wp)[2] = o2; ((float4*)wp)[3] = o3;
    }

    // PV
#pragma unroll
    for (int kk2 = 0; kk2 < 2; ++kk2) {
      const bf16x8 pa = *(const bf16x8*)((char*)pl + fr * 128 + (((kk2 * 4 + fq) ^ (fr & 7)) * 16));
#pragma unroll
      for (int jn2 = 0; jn2 < 8; ++jn2) {
        const int d = jn2 * 16 + fr;
        const bf16x8 vb = *(const bf16x8*)&Vs[d * 64 + (((kk2 * 4 + fq) ^ (d & 7)) * 8)];
        acc2[jn2] = __builtin_amdgcn_mfma_f32_16x16x32_bf16(pa, vb, acc2[jn2], 0, 0, 0);
      }
    }
  }

  // epilogue: attn -> bf16 [B*S][NH*HD]
#pragma unroll
  for (int e = 0; e < 4; ++e) {
    const int qrow = qw0 + fq * 4 + e;
#pragma unroll
    for (int jn2 = 0; jn2 < 8; ++jn2)
      attnb[((size_t)b * Ss + qrow) * HID + h * HD + jn2 * 16 + fr] =
          f2bf(acc2[jn2][e] * scl[e]);
  }
}

// ---------------------------------------------------------------------------
// One-shot fp32 -> bf16 conversion of hs + all 4 weights (segmented grid).
constexpr int CB_HS = Bb * Ss * HID / 2048;       // 4096
constexpr int CB_WQ = NH * HD * HID / 2048;       // 8192
constexpr int CB_WK = NKV * HD * HID / 2048;      // 2048
constexpr int CB_WV = CB_WK;                      // 2048
constexpr int CB_WO = HID * NH * HD / 2048;       // 8192

__global__ __launch_bounds__(256) void convert_all(
    const float* __restrict__ hs, const float* __restrict__ wq,
    const float* __restrict__ wk, const float* __restrict__ wv,
    const float* __restrict__ wo,
    u16* __restrict__ hsb, u16* __restrict__ wqb, u16* __restrict__ wkb,
    u16* __restrict__ wvb, u16* __restrict__ wob) {
  const int bid = blockIdx.x;
  const float* src;
  u16* dst;
  int base;
  if (bid < CB_HS) { src = hs; dst = hsb; base = 0; }
  else if (bid < CB_HS + CB_WQ) { src = wq; dst = wqb; base = CB_HS; }
  else if (bid < CB_HS + CB_WQ + CB_WK) { src = wk; dst = wkb; base = CB_HS + CB_WQ; }
  else if (bid < CB_HS + CB_WQ + CB_WK + CB_WV) { src = wv; dst = wvb; base = CB_HS + CB_WQ + CB_WK; }
  else { src = wo; dst = wob; base = CB_HS + CB_WQ + CB_WK + CB_WV; }
  const int i = (bid - base) * 256 + threadIdx.x;
  float4 a = ((const float4*)src)[2 * i];
  float4 b = ((const float4*)src)[2 * i + 1];
  u16x8 t;
  t[0] = f2bf(a.x); t[1] = f2bf(a.y); t[2] = f2bf(a.z); t[3] = f2bf(a.w);
  t[4] = f2bf(b.x); t[5] = f2bf(b.y); t[6] = f2bf(b.z); t[7] = f2bf(b.w);
  ((u16x8*)dst)[i] = t;
}

// RoPE + per-row asymmetric 8-bit fake-quant for q -> bf16. One wave per row.
__global__ __launch_bounds__(256) void rope_quant_q(const float* __restrict__ q,
                                                    u16* __restrict__ qb,
                                                    const float* __restrict__ cs,
                                                    const float* __restrict__ sn) {
  const int row = blockIdx.x * 4 + (threadIdx.x >> 6);
  const int lane = threadIdx.x & 63;
  const int s = row & (Ss - 1);
  const int b = row >> 15;
  const float* p = q + (size_t)row * HD;
  const float* cp = cs + ((size_t)b * Ss + s) * HD;
  const float* sp = sn + ((size_t)b * Ss + s) * HD;
  float x1 = p[lane], x2 = p[lane + 64];
  float r1 = x1 * cp[lane] - x2 * sp[lane];
  float r2 = x2 * cp[lane + 64] + x1 * sp[lane + 64];
  float mn = fminf(0.f, fminf(r1, r2));
  float mx = fmaxf(0.f, fmaxf(r1, r2));
#pragma unroll
  for (int o = 32; o; o >>= 1) {
    mn = fminf(mn, __shfl_xor(mn, o));
    mx = fmaxf(mx, __shfl_xor(mx, o));
  }
  float rng = mx - mn;
  float scale = (rng == 0.f) ? 1.f : rng / 255.f;
  float zero = rintf(-mn / scale);
  float q1 = fminf(fmaxf(rintf(r1 / scale) + zero, 0.f), 255.f);
  float q2 = fminf(fmaxf(rintf(r2 / scale) + zero, 0.f), 255.f);
  qb[(size_t)row * HD + lane] = f2bf((q1 - zero) * scale);
  qb[(size_t)row * HD + lane + 64] = f2bf((q2 - zero) * scale);
}

// RoPE only for k. One wave per row, in place.
__global__ __launch_bounds__(256) void rope_k(float* __restrict__ k,
                                              const float* __restrict__ cs,
                                              const float* __restrict__ sn) {
  const int row = blockIdx.x * 4 + (threadIdx.x >> 6);
  const int lane = threadIdx.x & 63;
  const int s = row & (Ss - 1);
  const int b = row >> 13;
  float* p = k + (size_t)row * HD;
  const float* cp = cs + ((size_t)b * Ss + s) * HD;
  const float* sp = sn + ((size_t)b * Ss + s) * HD;
  float x1 = p[lane], x2 = p[lane + 64];
  float r1 = x1 * cp[lane] - x2 * sp[lane];
  float r2 = x2 * cp[lane + 64] + x1 * sp[lane + 64];
  p[lane] = r1;
  p[lane + 64] = r2;
}

// Mean of k over S per (b,h,d). One 1024-thread block per (b,h).
__global__ __launch_bounds__(1024) void kmean_kernel(const float* __restrict__ k,
                                                     float* __restrict__ kmean) {
  const int bh = blockIdx.x;
  const int d = threadIdx.x & 127;
  const int sl = threadIdx.x >> 7;
  const float* p = k + (size_t)bh * Ss * HD;
  float sum = 0.f;
  for (int s = sl; s < Ss; s += 8) sum += p[(size_t)s * HD + d];
  __shared__ float lds[8][128];
  lds[sl][d] = sum;
  __syncthreads();
  if (threadIdx.x < 128) {
    float t = 0.f;
#pragma unroll
    for (int i = 0; i < 8; i++) t += lds[i][threadIdx.x];
    kmean[bh * HD + threadIdx.x] = t * (1.f / 1024.f);
  }
}

// Subtract mean + per-row quant for k -> bf16. One wave per row.
__global__ __launch_bounds__(256) void k_subquant(const float* __restrict__ k,
                                                  u16* __restrict__ kb,
                                                  const float* __restrict__ kmean) {
  const int row = blockIdx.x * 4 + (threadIdx.x >> 6);
  const int lane = threadIdx.x & 63;
  const int bh = row >> 10;
  const float* p = k + (size_t)row * HD;
  float x1 = p[lane] - kmean[bh * HD + lane];
  float x2 = p[lane + 64] - kmean[bh * HD + lane + 64];
  float mn = fminf(0.f, fminf(x1, x2));
  float mx = fmaxf(0.f, fmaxf(x1, x2));
#pragma unroll
  for (int o = 32; o; o >>= 1) {
    mn = fminf(mn, __shfl_xor(mn, o));
    mx = fmaxf(mx, __shfl_xor(mx, o));
  }
  float rng = mx - mn;
  float scale = (rng == 0.f) ? 1.f : rng / 255.f;
  float zero = rintf(-mn / scale);
  float q1 = fminf(fmaxf(rintf(x1 / scale) + zero, 0.f), 255.f);
  float q2 = fminf(fmaxf(rintf(x2 / scale) + zero, 0.f), 255.f);
  kb[(size_t)row * HD + lane] = f2bf((q1 - zero) * scale);
  kb[(size_t)row * HD + lane + 64] = f2bf((q2 - zero) * scale);
}

// Per-(b,h,d) quant of v over S (vT rows) -> bf16. One block per row.
__global__ __launch_bounds__(256) void vquant(const float* __restrict__ vT,
                                              u16* __restrict__ vTb) {
  const float* p = vT + (size_t)blockIdx.x * Ss;
  const int t = threadIdx.x;
  float4 x = ((const float4*)p)[t];
  float mn = fminf(0.f, fminf(fminf(x.x, x.y), fminf(x.z, x.w)));
  float mx = fmaxf(0.f, fmaxf(fmaxf(x.x, x.y), fmaxf(x.z, x.w)));
#pragma unroll
  for (int o = 32; o; o >>= 1) {
    mn = fminf(mn, __shfl_xor(mn, o));
    mx = fmaxf(mx, __shfl_xor(mx, o));
  }
  __shared__ float smn[4], smx[4];
  const int wid = t >> 6, lane = t & 63;
  if (lane == 0) { smn[wid] = mn; smx[wid] = mx; }
  __syncthreads();
  mn = fminf(fminf(smn[0], smn[1]), fminf(smn[2], smn[3]));
  mx = fmaxf(fmaxf(smx[0], smx[1]), fmaxf(smx[2], smx[3]));
  float rng = mx - mn;
  float scale = (rng == 0.f) ? 1.f : rng / 255.f;
  float zero = rintf(-mn / scale);
  u16x4 o4;
  o4[0] = f2bf((fminf(fmaxf(rintf(x.x / scale) + zero, 0.f), 255.f) - zero) * scale);
  o4[1] = f2bf((fminf(fmaxf(rintf(x.y / scale) + zero, 0.f), 255.f) - zero) * scale);
  o4[2] = f2bf((fminf(fmaxf(rintf(x.z / scale) + zero, 0.f), 255.f) - zero) * scale);
  o4[3] = f2bf((fminf(fmaxf(rintf(x.w / scale) + zero, 0.f), 255.f) - zero) * scale);
  ((u16x4*)vTb)[(size_t)blockIdx.x * 256 + t] = o4;
}

// ---------------------------------------------------------------------------
extern "C" void kernel_launch(void* const* d_in, const int* in_sizes, int n_in,
                              void* d_out, int out_size, void* d_ws, size_t ws_size,
                              hipStream_t stream) {
  const float* hs = (const float*)d_in[0];
  const float* cosp = (const float*)d_in[1];
  const float* sinp = (const float*)d_in[2];
  const float* Wq = (const float*)d_in[4];
  const float* Wk = (const float*)d_in[5];
  const float* Wv = (const float*)d_in[6];
  const float* Wo = (const float*)d_in[7];

  float* out = (float*)d_out;
  float* wout = out + (size_t)Bb * Ss * HID;  // w output region (fp32)

  char* wsp = (char*)d_ws;
  auto alloc = [&](size_t bytes) {
    char* p = wsp;
    wsp += (bytes + 255) & ~(size_t)255;
    return p;
  };
  float* q     = (float*)alloc((size_t)Bb * NH * Ss * HD * 4);   // 33.6 MB
  float* k     = (float*)alloc((size_t)Bb * NKV * Ss * HD * 4);  // 8.4 MB
  float* vT    = (float*)alloc((size_t)Bb * NKV * Ss * HD * 4);  // 8.4 MB
  float* kmean = (float*)alloc((size_t)Bb * NKV * HD * 4);
  u16* hsb = (u16*)alloc((size_t)Bb * Ss * HID * 2);
  u16* qb  = (u16*)alloc((size_t)Bb * NH * Ss * HD * 2);
  u16* kb  = (u16*)alloc((size_t)Bb * NKV * Ss * HD * 2);
  u16* vTb = (u16*)alloc((size_t)Bb * NKV * Ss * HD * 2);
  u16* Wqb = (u16*)alloc((size_t)NH * HD * HID * 2);
  u16* Wkb = (u16*)alloc((size_t)NKV * HD * HID * 2);
  u16* Wvb = (u16*)alloc((size_t)NKV * HD * HID * 2);
  u16* Wob = (u16*)alloc((size_t)HID * NH * HD * 2);
  u16* attnb = (u16*)q;  // q fp32 dead after rope_quant_q; reuse

  // fp32 -> bf16 conversions (single dispatch)
  convert_all<<<CB_HS + CB_WQ + CB_WK + CB_WV + CB_WO, 256, 0, stream>>>(
      hs, Wq, Wk, Wv, Wo, hsb, Wqb, Wkb, Wvb, Wob);

  // fused Q/K/V projection (128x256 tiles, 24 x 16 = 384 blocks)
  mfma_gemm<M_QKV><<<dim3(24, 16), 512, 0, stream>>>(
      hsb, Wqb, Wkb, Wvb, q, k, vT, HID);

  // RoPE / mean-center / quantize
  rope_quant_q<<<(Bb * NH * Ss) / 4, 256, 0, stream>>>(q, qb, cosp, sinp);
  rope_k<<<(Bb * NKV * Ss) / 4, 256, 0, stream>>>(k, cosp, sinp);
  kmean_kernel<<<Bb * NKV, 1024, 0, stream>>>(k, kmean);
  k_subquant<<<(Bb * NKV * Ss) / 4, 256, 0, stream>>>(k, kb, kmean);
  vquant<<<Bb * NKV * HD, 256, 0, stream>>>(vT, vTb);

  // fused scores+softmax+quant(w)+PV  (1024 uniform-work blocks, heavy first)
  fused_attn<<<dim3(1024), 256, 0, stream>>>(qb, kb, vTb, wout, attnb);

  // out = attn @ Wo^T (128x256 tiles, 16 x 16 = 256 blocks = 1/CU)
  mfma_gemm<M_OUT><<<dim3(16, 16), 512, 0, stream>>>(
      attnb, Wob, nullptr, nullptr, out, nullptr, nullptr, HID);
}